// Round 4
// baseline (609.661 us; speedup 1.0000x reference)
//
#include <hip/hip_runtime.h>

#define N_NODES 50000
#define N_EDGES 800000
#define N_GRAPHS 512
#define IN_C 128
#define HID 256
#define OUT_C 16

typedef __attribute__((ext_vector_type(8))) short short8;
typedef __attribute__((ext_vector_type(4))) float f32x4;

__device__ __forceinline__ float bf2f(unsigned short u) {
    return __uint_as_float(((unsigned int)u) << 16);
}
__device__ __forceinline__ unsigned short f2bf(float f) {
    unsigned int u = __float_as_uint(f);
    u += 0x7fff + ((u >> 16) & 1);   // RNE
    return (unsigned short)(u >> 16);
}

// Planar layout: features stored as [C/32 planes][N_NODES][32 cols] bf16.
// Each plane is 50000*64B = 3.2 MB (contiguous) -> fits one XCD's 4 MB L2.
#define PLANE_ELEMS ((long)N_NODES * 32)

// ===========================================================================
// Prep (single dispatch): x -> bf16 PLANAR, six weight transposes (K x 256
// fp32 -> 256 x K bf16), zero deg+hist, zero sums.
// deg and hist are contiguous in the workspace; zeroed together.
// ===========================================================================
struct PrepArgs {
    const float* x;
    const float* w[6];      // K x 256 row-major; K = 128 for w[0], else 256
    ushort* xbf;            // planar [4][N][32]
    ushort* wt[6];
    int* deg;               // N_NODES + 256 (hist) ints, contiguous
    float* sums;
};

__global__ __launch_bounds__(256) void prep_kernel(PrepArgs a) {
    const int X4    = N_NODES * IN_C / 4;
    const int TW    = IN_C * HID;
    const int TH    = HID * HID;
    const int TBASE = X4;
    const int TEND  = TBASE + TW + 5 * TH;
    const int D4    = N_NODES / 4 + 64;   // deg + 256-int hist
    const int DBASE = TEND;
    const int SBASE = DBASE + D4;
    const int S4    = N_GRAPHS * HID / 4;
    const long total = (long)SBASE + S4;

    long stride = (long)gridDim.x * blockDim.x;
    for (long i = (long)blockIdx.x * blockDim.x + threadIdx.x; i < total; i += stride) {
        if (i < X4) {
            float4 v = ((const float4*)a.x)[i];
            ushort4 o;
            o.x = f2bf(v.x); o.y = f2bf(v.y); o.z = f2bf(v.z); o.w = f2bf(v.w);
            long e = i * 4;
            int node = (int)(e >> 7);         // /128
            int col  = (int)(e & 127);
            long off = (long)(col >> 5) * PLANE_ELEMS + (long)node * 32 + (col & 31);
            *(ushort4*)(a.xbf + off) = o;
        } else if (i < TEND) {
            long r = i - TBASE;
            int wi, shift;
            long off;
            if (r < TW) { wi = 0; shift = 7; off = r; }
            else { r -= TW; wi = 1 + (int)(r / TH); shift = 8; off = r % TH; }
            int n = (int)(off >> shift);
            int k = (int)(off - ((long)n << shift));
            a.wt[wi][off] = f2bf(a.w[wi][(long)k * HID + n]);
        } else if (i < SBASE) {
            ((int4*)a.deg)[i - DBASE] = make_int4(0, 0, 0, 0);
        } else {
            ((float4*)a.sums)[i - SBASE] = make_float4(0.f, 0.f, 0.f, 0.f);
        }
    }
}

// ===========================================================================
// CSR build: deg histogram -> scan (2 fused dispatches) -> bucket by dst.
// scan_block additionally builds the degree histogram (for load balancing).
// ===========================================================================
__global__ void deg_kernel(const int* __restrict__ dst, int* __restrict__ deg) {
    int e = blockIdx.x * blockDim.x + threadIdx.x;
    if (e < N_EDGES) atomicAdd(&deg[dst[e]], 1);
}

__global__ __launch_bounds__(256) void scan_block(const int* __restrict__ deg,
                                                  int* __restrict__ partial,
                                                  int* __restrict__ blockSums,
                                                  int* __restrict__ hist) {
    __shared__ int s[256];
    __shared__ int hb[256];
    int t = threadIdx.x;
    int i = blockIdx.x * 256 + t;
    int v = (i < N_NODES) ? deg[i] : 0;
    hb[t] = 0;
    s[t] = v;
    __syncthreads();
    if (i < N_NODES) atomicAdd(&hb[v < 255 ? v : 255], 1);
    #pragma unroll
    for (int off = 1; off < 256; off <<= 1) {
        int add = (t >= off) ? s[t - off] : 0;
        __syncthreads();
        s[t] += add;
        __syncthreads();
    }
    if (i < N_NODES) partial[i] = s[t] - v;
    if (t == 255) blockSums[blockIdx.x] = s[255];
    __syncthreads();
    if (hb[t]) atomicAdd(&hist[t], hb[t]);
}

__global__ __launch_bounds__(256) void add_offsets_fused(
    const int* __restrict__ partial, const int* __restrict__ blockSums,
    int* __restrict__ rowptr, int* __restrict__ cursor, int nb) {
    __shared__ int s[256];
    __shared__ int myOff;
    int t = threadIdx.x;
    int v = (t < nb) ? blockSums[t] : 0;
    s[t] = v;
    __syncthreads();
    #pragma unroll
    for (int off = 1; off < 256; off <<= 1) {
        int add = (t >= off) ? s[t - off] : 0;
        __syncthreads();
        s[t] += add;
        __syncthreads();
    }
    if (t == blockIdx.x) myOff = s[t] - v;
    __syncthreads();
    int i = blockIdx.x * 256 + t;
    if (i < N_NODES) {
        int r = partial[i] + myOff;
        rowptr[i] = r;
        cursor[i] = r;
    }
    if (i == 0) rowptr[N_NODES] = N_EDGES;
}

__global__ void bucket_edges(const int* __restrict__ src, const int* __restrict__ dst,
                             int* __restrict__ cursor, int* __restrict__ srcSorted) {
    int e = blockIdx.x * blockDim.x + threadIdx.x;
    if (e >= N_EDGES) return;
    int p = atomicAdd(&cursor[dst[e]], 1);
    srcSorted[p] = src[e];
}

// ---- Degree counting-sort (descending): bin offsets + scatter ------------
__global__ __launch_bounds__(256) void hist_scan(const int* __restrict__ hist,
                                                 int* __restrict__ binCursor) {
    __shared__ int s[256];
    int t = threadIdx.x;
    int v = hist[255 - t];          // reversed -> descending degree order
    s[t] = v;
    __syncthreads();
    #pragma unroll
    for (int off = 1; off < 256; off <<= 1) {
        int add = (t >= off) ? s[t - off] : 0;
        __syncthreads();
        s[t] += add;
        __syncthreads();
    }
    binCursor[255 - t] = s[t] - v;
}

__global__ void perm_scatter(const int* __restrict__ deg, int* __restrict__ binCursor,
                             int* __restrict__ perm) {
    int i = blockIdx.x * blockDim.x + threadIdx.x;
    if (i >= N_NODES) return;
    int d = deg[i]; d = d < 255 ? d : 255;
    int p = atomicAdd(&binCursor[d], 1);
    perm[p] = i;
}

// ===========================================================================
// Aggregation, planar-in / row-major-out: out[n] = h[n] + sum h[src].
// Degree-balanced: slot -> node via perm[] (nodes counting-sorted by degree
// descending), so a wave's 16 node-groups have ~equal edge counts -> no
// exec-mask waste from Poisson degree spread. Edge loop unrolled x8.
// ===========================================================================
template <int C>
__global__ __launch_bounds__(256) void gin_aggregate_planar(
    const ushort* __restrict__ hp,     // planar [C/32][N][32]
    const int* __restrict__ rowptr,
    const int* __restrict__ srcIdx,
    const int* __restrict__ perm,
    ushort* __restrict__ out)          // row-major [N][C]
{
    constexpr int NC  = C / 32;        // 4 (C=128) or 8 (C=256)
    constexpr int PER = 8 / NC;        // XCDs per plane (2 or 1)

    int b  = blockIdx.x;
    int x8 = b & 7;                    // presumed XCD id (round-robin)
    int chunk   = x8 / PER;
    int nodeblk = (b >> 3) * PER + (x8 & (PER - 1));

    int lane = threadIdx.x & 63;
    int wave = threadIdx.x >> 6;
    int grp  = lane >> 2;              // 0..15: node within wave
    int l    = lane & 3;               // 4 lanes x 8 bf16 = 32 cols
    int slot = nodeblk * 64 + wave * 16 + grp;
    if (slot >= N_NODES) return;
    int node = perm[slot];

    const ushort* plane = hp + (long)chunk * PLANE_ELEMS + l * 8;

    float acc[8];
    {
        short8 sv = *(const short8*)(plane + (long)node * 32);
        #pragma unroll
        for (int v = 0; v < 8; ++v) acc[v] = bf2f((unsigned short)sv[v]);
    }

    int beg = rowptr[node], end = rowptr[node + 1];
    int k = beg;
    for (; k + 8 <= end; k += 8) {
        int si[8];
        #pragma unroll
        for (int u = 0; u < 8; ++u) si[u] = srcIdx[k + u];
        short8 r[8];
        #pragma unroll
        for (int u = 0; u < 8; ++u) r[u] = *(const short8*)(plane + (long)si[u] * 32);
        #pragma unroll
        for (int u = 0; u < 8; ++u)
            #pragma unroll
            for (int v = 0; v < 8; ++v) acc[v] += bf2f((unsigned short)r[u][v]);
    }
    for (; k + 2 <= end; k += 2) {
        int si0 = srcIdx[k], si1 = srcIdx[k + 1];
        short8 r0 = *(const short8*)(plane + (long)si0 * 32);
        short8 r1 = *(const short8*)(plane + (long)si1 * 32);
        #pragma unroll
        for (int v = 0; v < 8; ++v) acc[v] += bf2f((unsigned short)r0[v]);
        #pragma unroll
        for (int v = 0; v < 8; ++v) acc[v] += bf2f((unsigned short)r1[v]);
    }
    if (k < end) {
        short8 r = *(const short8*)(plane + (long)srcIdx[k] * 32);
        #pragma unroll
        for (int v = 0; v < 8; ++v) acc[v] += bf2f((unsigned short)r[v]);
    }

    short8 o;
    #pragma unroll
    for (int v = 0; v < 8; ++v) o[v] = (short)f2bf(acc[v]);
    *(short8*)(out + (long)node * C + chunk * 32 + l * 8) = o;
}

// ===========================================================================
// Fused 2-layer MLP, weights-in-registers (unchanged from round 3).
// ===========================================================================
template <int K1, bool FUSE_POOL>
__global__ __launch_bounds__(512, 4) void gin_mlp(
    const ushort* __restrict__ A,
    const ushort* __restrict__ w1t,
    const float* __restrict__ b1,
    const ushort* __restrict__ w2t,
    const float* __restrict__ b2,
    ushort* __restrict__ out,          // planar [8][N][32]
    const int* __restrict__ batch,
    float* __restrict__ sums,
    int M)
{
    __shared__ short Ls[2048 * 8];      // 32 KB

    constexpr int NCH1 = K1 / 8;        // 16 or 32
    constexpr int NSLOT1 = 64 * NCH1;   // 1024 or 2048
    constexpr int NS1 = K1 / 32;        // 4 or 8

    int t = threadIdx.x;
    int lane = t & 63;
    int wv = t >> 6;                    // 0..7
    int quad = lane >> 4;
    int l15 = lane & 15;
    int swz = l15 & 7;
    int row0 = blockIdx.x * 64;
    int col0 = wv * 32;

    // ---- Preload W1 slice into registers ----
    short8 bw[16];
    #pragma unroll
    for (int s = 0; s < NS1; ++s)
        #pragma unroll
        for (int j = 0; j < 2; ++j)
            bw[s * 2 + j] = *(const short8*)(w1t + (long)(col0 + j * 16 + l15) * K1 + s * 32 + quad * 8);

    float bv[2];
    #pragma unroll
    for (int j = 0; j < 2; ++j) bv[j] = b1[col0 + j * 16 + l15];

    // ---- Stage A tile (64 x K1, source-side swizzle) ----
    #pragma unroll
    for (int c = 0; c < NSLOT1; c += 512) {
        int s = c + t;
        int row = s / NCH1;
        int kcs = s & (NCH1 - 1);
        int kc = kcs ^ (row & 7);
        int grow = row0 + row;
        if (grow >= M) grow = M - 1;
        short8 v = *(const short8*)(A + (long)grow * K1 + kc * 8);
        *(short8*)&Ls[s * 8] = v;
    }
    __syncthreads();

    const f32x4 zero = {0.f, 0.f, 0.f, 0.f};
    f32x4 acc[4][2];
    #pragma unroll
    for (int i = 0; i < 4; ++i)
        #pragma unroll
        for (int j = 0; j < 2; ++j) acc[i][j] = zero;

    // ---- Layer 1: K-loop, LDS + registers only ----
    #pragma unroll
    for (int s = 0; s < NS1; ++s) {
        #pragma unroll
        for (int i = 0; i < 4; ++i) {
            int row = i * 16 + l15;
            int slot = row * NCH1 + ((s * 4 + quad) ^ swz);
            short8 a = *(const short8*)&Ls[slot * 8];
            acc[i][0] = __builtin_amdgcn_mfma_f32_16x16x32_bf16(a, bw[s * 2 + 0], acc[i][0], 0, 0, 0);
            acc[i][1] = __builtin_amdgcn_mfma_f32_16x16x32_bf16(a, bw[s * 2 + 1], acc[i][1], 0, 0, 0);
        }
    }

    // ---- Preload W2 slice (reuse bw regs); latency hides under barriers ----
    #pragma unroll
    for (int s = 0; s < 8; ++s)
        #pragma unroll
        for (int j = 0; j < 2; ++j)
            bw[s * 2 + j] = *(const short8*)(w2t + (long)(col0 + j * 16 + l15) * 256 + s * 32 + quad * 8);

    __syncthreads();

    // ---- H = relu(acc + b1) -> LDS (swizzled 64 x 256 bf16) ----
    #pragma unroll
    for (int i = 0; i < 4; ++i)
        #pragma unroll
        for (int j = 0; j < 2; ++j) {
            int col = col0 + j * 16 + l15;
            int kc2 = col >> 3, sub = col & 7;
            #pragma unroll
            for (int r = 0; r < 4; ++r) {
                int row = i * 16 + quad * 4 + r;
                int slot = row * 32 + (kc2 ^ (row & 7));
                float o = fmaxf(acc[i][j][r] + bv[j], 0.f);
                Ls[slot * 8 + sub] = (short)f2bf(o);
            }
        }

    #pragma unroll
    for (int j = 0; j < 2; ++j) bv[j] = b2[col0 + j * 16 + l15];

    __syncthreads();

    #pragma unroll
    for (int i = 0; i < 4; ++i)
        #pragma unroll
        for (int j = 0; j < 2; ++j) acc[i][j] = zero;

    // ---- Layer 2: K-loop, LDS + registers only ----
    #pragma unroll
    for (int s = 0; s < 8; ++s) {
        #pragma unroll
        for (int i = 0; i < 4; ++i) {
            int row = i * 16 + l15;
            int slot = row * 32 + ((s * 4 + quad) ^ swz);
            short8 a = *(const short8*)&Ls[slot * 8];
            acc[i][0] = __builtin_amdgcn_mfma_f32_16x16x32_bf16(a, bw[s * 2 + 0], acc[i][0], 0, 0, 0);
            acc[i][1] = __builtin_amdgcn_mfma_f32_16x16x32_bf16(a, bw[s * 2 + 1], acc[i][1], 0, 0, 0);
        }
    }

    if constexpr (!FUSE_POOL) {
        #pragma unroll
        for (int i = 0; i < 4; ++i)
            #pragma unroll
            for (int r = 0; r < 4; ++r) {
                int row = row0 + i * 16 + quad * 4 + r;
                if (row >= M) continue;
                #pragma unroll
                for (int j = 0; j < 2; ++j) {
                    int col = col0 + j * 16 + l15;
                    float o = fmaxf(acc[i][j][r] + bv[j], 0.f);
                    out[(long)(col >> 5) * PLANE_ELEMS + (long)row * 32 + (col & 31)] = f2bf(o);
                }
            }
    } else {
        float pacc[2];
        #pragma unroll
        for (int j = 0; j < 2; ++j) pacc[j] = 0.f;
        int cur = -1;
        #pragma unroll
        for (int i = 0; i < 4; ++i) {
            #pragma unroll
            for (int r = 0; r < 4; ++r) {
                int row = row0 + i * 16 + quad * 4 + r;
                if (row >= M) continue;
                int g = batch[row];
                if (g != cur) {
                    if (cur >= 0) {
                        #pragma unroll
                        for (int j = 0; j < 2; ++j)
                            atomicAdd(&sums[(long)cur * 256 + col0 + j * 16 + l15], pacc[j]);
                    }
                    cur = g;
                    #pragma unroll
                    for (int j = 0; j < 2; ++j) pacc[j] = 0.f;
                }
                #pragma unroll
                for (int j = 0; j < 2; ++j)
                    pacc[j] += fmaxf(acc[i][j][r] + bv[j], 0.f);
            }
        }
        if (cur >= 0) {
            #pragma unroll
            for (int j = 0; j < 2; ++j)
                atomicAdd(&sums[(long)cur * 256 + col0 + j * 16 + l15], pacc[j]);
        }
    }
}

// ===========================================================================
// Head MLP (fp32): one block per graph; count via binary search on batch.
// ===========================================================================
__global__ __launch_bounds__(256) void final_mlp_kernel(
    const float* __restrict__ sums, const int* __restrict__ batch,
    const float* __restrict__ w1, const float* __restrict__ b1,
    const float* __restrict__ w2, const float* __restrict__ b2,
    float* __restrict__ out) {
    __shared__ float row[HID];
    __shared__ float hid[HID];
    __shared__ int cntS;
    int g = blockIdx.x;
    int t = threadIdx.x;
    if (t == 0) {
        int lo = 0, hi = N_NODES;
        while (lo < hi) { int m = (lo + hi) >> 1; if (batch[m] < g) lo = m + 1; else hi = m; }
        int lo2 = lo, hi2 = N_NODES;
        while (lo2 < hi2) { int m = (lo2 + hi2) >> 1; if (batch[m] < g + 1) lo2 = m + 1; else hi2 = m; }
        cntS = lo2 - lo;
    }
    __syncthreads();
    float cnt = fmaxf((float)cntS, 1.0f);
    row[t] = sums[(long)g * HID + t] / cnt;
    __syncthreads();
    float acc = b1[t];
    for (int k = 0; k < HID; ++k) acc += row[k] * w1[k * HID + t];
    hid[t] = fmaxf(acc, 0.f);
    __syncthreads();
    if (t < OUT_C) {
        float o = b2[t];
        for (int k = 0; k < HID; ++k) o += hid[k] * w2[k * OUT_C + t];
        out[(long)g * OUT_C + t] = o;
    }
}

// ---------------------------------------------------------------------------
extern "C" void kernel_launch(void* const* d_in, const int* in_sizes, int n_in,
                              void* d_out, int out_size, void* d_ws, size_t ws_size,
                              hipStream_t stream) {
    const float* x     = (const float*)d_in[0];
    const int*   ei    = (const int*)d_in[1];
    const int*   batch = (const int*)d_in[2];
    const int*   src   = ei;
    const int*   dst   = ei + N_EDGES;

    const float* c_w1[3] = { (const float*)d_in[3],  (const float*)d_in[7],  (const float*)d_in[11] };
    const float* c_b1[3] = { (const float*)d_in[4],  (const float*)d_in[8],  (const float*)d_in[12] };
    const float* c_w2[3] = { (const float*)d_in[5],  (const float*)d_in[9],  (const float*)d_in[13] };
    const float* c_b2[3] = { (const float*)d_in[6],  (const float*)d_in[10], (const float*)d_in[14] };
    const float* out_w1 = (const float*)d_in[15];
    const float* out_b1 = (const float*)d_in[16];
    const float* out_w2 = (const float*)d_in[17];
    const float* out_b2 = (const float*)d_in[18];

    // ---- Workspace layout (16B aligned) ----
    char* p = (char*)d_ws;
    auto alloc = [&](size_t bytes) {
        char* r = p;
        p += (bytes + 15) & ~(size_t)15;
        return r;
    };
    ushort* xbf  = (ushort*)alloc((size_t)N_NODES * IN_C * 2);   // planar [4][N][32]
    ushort* bufA = (ushort*)alloc((size_t)N_NODES * HID * 2);    // planar [8][N][32]
    ushort* bufB = (ushort*)alloc((size_t)N_NODES * HID * 2);    // row-major agg output
    ushort* wt[6];
    wt[0] = (ushort*)alloc((size_t)IN_C * HID * 2);
    for (int i = 1; i < 6; ++i) wt[i] = (ushort*)alloc((size_t)HID * HID * 2);
    float* sums   = (float*)alloc((size_t)N_GRAPHS * HID * 4);
    int* deg       = (int*)alloc((size_t)N_NODES * 4);   // N*4 = 200000 B, 16-aligned
    int* hist      = (int*)alloc(256 * 4);               // contiguous after deg
    int* rowptr    = (int*)alloc((size_t)(N_NODES + 1) * 4);
    int* blockSums = (int*)alloc(256 * 4);
    int* cursor    = (int*)alloc((size_t)N_NODES * 4);
    int* binCursor = (int*)alloc(256 * 4);
    int* perm      = (int*)alloc((size_t)N_NODES * 4);
    int* srcSorted = (int*)alloc((size_t)N_EDGES * 4);

    const int nb = (N_NODES + 255) / 256;

    // ---- Prep: one dispatch for casts + transposes + zeroing ----
    {
        PrepArgs a;
        a.x = x;
        a.w[0] = c_w1[0]; a.w[1] = c_w2[0];
        a.w[2] = c_w1[1]; a.w[3] = c_w2[1];
        a.w[4] = c_w1[2]; a.w[5] = c_w2[2];
        a.xbf = xbf;
        for (int i = 0; i < 6; ++i) a.wt[i] = wt[i];
        a.deg = deg;     // zeroes deg + hist (contiguous)
        a.sums = sums;
        prep_kernel<<<2048, 256, 0, stream>>>(a);
    }

    // ---- Build CSR by dst + degree-balanced permutation ----
    deg_kernel<<<(N_EDGES + 255) / 256, 256, 0, stream>>>(dst, deg);
    scan_block<<<nb, 256, 0, stream>>>(deg, rowptr, blockSums, hist);
    add_offsets_fused<<<nb, 256, 0, stream>>>(rowptr, blockSums, rowptr, cursor, nb);
    bucket_edges<<<(N_EDGES + 255) / 256, 256, 0, stream>>>(src, dst, cursor, srcSorted);
    hist_scan<<<1, 256, 0, stream>>>(hist, binCursor);
    perm_scatter<<<nb, 256, 0, stream>>>(deg, binCursor, perm);

    const int nodeBlks = (N_NODES + 63) / 64;        // 782 (even, needed for PER=2)
    const int aggX128  = nodeBlks * (IN_C / 32);     // 3128
    const int aggX256  = nodeBlks * (HID / 32);      // 6256
    const int mlpGrid  = (N_NODES + 63) / 64;        // 782

    // ---- Layer 0 (C_in = 128) ----
    gin_aggregate_planar<IN_C><<<aggX128, 256, 0, stream>>>(xbf, rowptr, srcSorted, perm, bufB);
    gin_mlp<IN_C, false><<<mlpGrid, 512, 0, stream>>>(bufB, wt[0], c_b1[0], wt[1], c_b2[0],
                                                      bufA, batch, sums, N_NODES);

    // ---- Layer 1 (C = 256) ----
    gin_aggregate_planar<HID><<<aggX256, 256, 0, stream>>>(bufA, rowptr, srcSorted, perm, bufB);
    gin_mlp<HID, false><<<mlpGrid, 512, 0, stream>>>(bufB, wt[2], c_b1[1], wt[3], c_b2[1],
                                                     bufA, batch, sums, N_NODES);

    // ---- Layer 2 (C = 256) with fused global mean-pool accumulation ----
    gin_aggregate_planar<HID><<<aggX256, 256, 0, stream>>>(bufA, rowptr, srcSorted, perm, bufB);
    gin_mlp<HID, true><<<mlpGrid, 512, 0, stream>>>(bufB, wt[4], c_b1[2], wt[5], c_b2[2],
                                                    bufA, batch, sums, N_NODES);

    // ---- Head MLP ----
    final_mlp_kernel<<<N_GRAPHS, 256, 0, stream>>>(sums, batch, out_w1, out_b1,
                                                   out_w2, out_b2, (float*)d_out);
}

// Round 5
// 527.007 us; speedup vs baseline: 1.1568x; 1.1568x over previous
//
#include <hip/hip_runtime.h>

#define N_NODES 50000
#define N_EDGES 800000
#define N_GRAPHS 512
#define IN_C 128
#define HID 256
#define OUT_C 16

typedef __attribute__((ext_vector_type(8))) short short8;
typedef __attribute__((ext_vector_type(4))) float f32x4;

__device__ __forceinline__ float bf2f(unsigned short u) {
    return __uint_as_float(((unsigned int)u) << 16);
}
__device__ __forceinline__ unsigned short f2bf(float f) {
    unsigned int u = __float_as_uint(f);
    u += 0x7fff + ((u >> 16) & 1);   // RNE
    return (unsigned short)(u >> 16);
}

// Planar layout: features stored as [C/32 planes][N_NODES][32 cols] bf16.
// Each plane is 50000*64B = 3.2 MB (contiguous) -> fits one XCD's 4 MB L2.
#define PLANE_ELEMS ((long)N_NODES * 32)

// ===========================================================================
// Prep (single dispatch): x -> bf16 PLANAR, six weight transposes (K x 256
// fp32 -> 256 x K bf16), zero deg, zero sums.
// ===========================================================================
struct PrepArgs {
    const float* x;
    const float* w[6];      // K x 256 row-major; K = 128 for w[0], else 256
    ushort* xbf;            // planar [4][N][32]
    ushort* wt[6];
    int* deg;
    float* sums;
};

__global__ __launch_bounds__(256) void prep_kernel(PrepArgs a) {
    const int X4    = N_NODES * IN_C / 4;
    const int TW    = IN_C * HID;
    const int TH    = HID * HID;
    const int TBASE = X4;
    const int TEND  = TBASE + TW + 5 * TH;
    const int D4    = N_NODES / 4;
    const int DBASE = TEND;
    const int SBASE = DBASE + D4;
    const int S4    = N_GRAPHS * HID / 4;
    const long total = (long)SBASE + S4;

    long stride = (long)gridDim.x * blockDim.x;
    for (long i = (long)blockIdx.x * blockDim.x + threadIdx.x; i < total; i += stride) {
        if (i < X4) {
            float4 v = ((const float4*)a.x)[i];
            ushort4 o;
            o.x = f2bf(v.x); o.y = f2bf(v.y); o.z = f2bf(v.z); o.w = f2bf(v.w);
            long e = i * 4;
            int node = (int)(e >> 7);         // /128
            int col  = (int)(e & 127);
            long off = (long)(col >> 5) * PLANE_ELEMS + (long)node * 32 + (col & 31);
            *(ushort4*)(a.xbf + off) = o;
        } else if (i < TEND) {
            long r = i - TBASE;
            int wi, shift;
            long off;
            if (r < TW) { wi = 0; shift = 7; off = r; }
            else { r -= TW; wi = 1 + (int)(r / TH); shift = 8; off = r % TH; }
            int n = (int)(off >> shift);
            int k = (int)(off - ((long)n << shift));
            a.wt[wi][off] = f2bf(a.w[wi][(long)k * HID + n]);
        } else if (i < SBASE) {
            ((int4*)a.deg)[i - DBASE] = make_int4(0, 0, 0, 0);
        } else {
            ((float4*)a.sums)[i - SBASE] = make_float4(0.f, 0.f, 0.f, 0.f);
        }
    }
}

// ===========================================================================
// CSR build: deg histogram -> scan (2 fused dispatches) -> bucket by dst.
// ===========================================================================
__global__ void deg_kernel(const int* __restrict__ dst, int* __restrict__ deg) {
    int e = blockIdx.x * blockDim.x + threadIdx.x;
    if (e < N_EDGES) atomicAdd(&deg[dst[e]], 1);
}

__global__ __launch_bounds__(256) void scan_block(const int* __restrict__ deg,
                                                  int* __restrict__ partial,
                                                  int* __restrict__ blockSums) {
    __shared__ int s[256];
    int t = threadIdx.x;
    int i = blockIdx.x * 256 + t;
    int v = (i < N_NODES) ? deg[i] : 0;
    s[t] = v;
    __syncthreads();
    #pragma unroll
    for (int off = 1; off < 256; off <<= 1) {
        int add = (t >= off) ? s[t - off] : 0;
        __syncthreads();
        s[t] += add;
        __syncthreads();
    }
    if (i < N_NODES) partial[i] = s[t] - v;
    if (t == 255) blockSums[blockIdx.x] = s[255];
}

__global__ __launch_bounds__(256) void add_offsets_fused(
    const int* __restrict__ partial, const int* __restrict__ blockSums,
    int* __restrict__ rowptr, int* __restrict__ cursor, int nb) {
    __shared__ int s[256];
    __shared__ int myOff;
    int t = threadIdx.x;
    int v = (t < nb) ? blockSums[t] : 0;
    s[t] = v;
    __syncthreads();
    #pragma unroll
    for (int off = 1; off < 256; off <<= 1) {
        int add = (t >= off) ? s[t - off] : 0;
        __syncthreads();
        s[t] += add;
        __syncthreads();
    }
    if (t == blockIdx.x) myOff = s[t] - v;
    __syncthreads();
    int i = blockIdx.x * 256 + t;
    if (i < N_NODES) {
        int r = partial[i] + myOff;
        rowptr[i] = r;
        cursor[i] = r;
    }
    if (i == 0) rowptr[N_NODES] = N_EDGES;
}

__global__ void bucket_edges(const int* __restrict__ src, const int* __restrict__ dst,
                             int* __restrict__ cursor, int* __restrict__ srcSorted) {
    int e = blockIdx.x * blockDim.x + threadIdx.x;
    if (e >= N_EDGES) return;
    int p = atomicAdd(&cursor[dst[e]], 1);
    srcSorted[p] = src[e];
}

// ===========================================================================
// Aggregation, planar-in / row-major-out: out[n] = h[n] + sum h[src].
//
// Streaming traffic (index reads, output writes) uses non-temporal hints so
// it does NOT allocate in L2 -> the 3.2 MB feature plane stays resident in
// its XCD's 4 MB L2 (round-3 FETCH=62.5MB vs ~29MB ideal = write-eviction
// re-fetch; this targets that 2.2x over-fetch).
// ===========================================================================
template <int C>
__global__ __launch_bounds__(256) void gin_aggregate_planar(
    const ushort* __restrict__ hp,     // planar [C/32][N][32]
    const int* __restrict__ rowptr,
    const int* __restrict__ srcIdx,
    ushort* __restrict__ out)          // row-major [N][C]
{
    constexpr int NC  = C / 32;        // 4 (C=128) or 8 (C=256)
    constexpr int PER = 8 / NC;        // XCDs per plane (2 or 1)

    int b  = blockIdx.x;
    int x8 = b & 7;                    // presumed XCD id (round-robin)
    int chunk   = x8 / PER;
    int nodeblk = (b >> 3) * PER + (x8 & (PER - 1));

    int lane = threadIdx.x & 63;
    int wave = threadIdx.x >> 6;
    int grp  = lane >> 2;              // 0..15: node within wave
    int l    = lane & 3;               // 4 lanes x 8 bf16 = 32 cols
    int node = nodeblk * 64 + wave * 16 + grp;
    if (node >= N_NODES) return;

    const ushort* plane = hp + (long)chunk * PLANE_ELEMS + l * 8;

    float acc[8];
    {
        short8 sv = *(const short8*)(plane + (long)node * 32);
        #pragma unroll
        for (int v = 0; v < 8; ++v) acc[v] = bf2f((unsigned short)sv[v]);
    }

    int beg = __builtin_nontemporal_load(rowptr + node);
    int end = __builtin_nontemporal_load(rowptr + node + 1);
    int k = beg;
    for (; k + 8 <= end; k += 8) {
        int si[8];
        #pragma unroll
        for (int u = 0; u < 8; ++u) si[u] = __builtin_nontemporal_load(srcIdx + k + u);
        short8 r[8];
        #pragma unroll
        for (int u = 0; u < 8; ++u) r[u] = *(const short8*)(plane + (long)si[u] * 32);
        #pragma unroll
        for (int u = 0; u < 8; ++u)
            #pragma unroll
            for (int v = 0; v < 8; ++v) acc[v] += bf2f((unsigned short)r[u][v]);
    }
    for (; k + 2 <= end; k += 2) {
        int si0 = __builtin_nontemporal_load(srcIdx + k);
        int si1 = __builtin_nontemporal_load(srcIdx + k + 1);
        short8 r0 = *(const short8*)(plane + (long)si0 * 32);
        short8 r1 = *(const short8*)(plane + (long)si1 * 32);
        #pragma unroll
        for (int v = 0; v < 8; ++v) acc[v] += bf2f((unsigned short)r0[v]);
        #pragma unroll
        for (int v = 0; v < 8; ++v) acc[v] += bf2f((unsigned short)r1[v]);
    }
    if (k < end) {
        int si0 = __builtin_nontemporal_load(srcIdx + k);
        short8 r = *(const short8*)(plane + (long)si0 * 32);
        #pragma unroll
        for (int v = 0; v < 8; ++v) acc[v] += bf2f((unsigned short)r[v]);
    }

    short8 o;
    #pragma unroll
    for (int v = 0; v < 8; ++v) o[v] = (short)f2bf(acc[v]);
    __builtin_nontemporal_store(o, (short8*)(out + (long)node * C + chunk * 32 + l * 8));
}

// ===========================================================================
// Fused 2-layer MLP, weights-in-registers (unchanged from round 3).
// ===========================================================================
template <int K1, bool FUSE_POOL>
__global__ __launch_bounds__(512, 4) void gin_mlp(
    const ushort* __restrict__ A,
    const ushort* __restrict__ w1t,
    const float* __restrict__ b1,
    const ushort* __restrict__ w2t,
    const float* __restrict__ b2,
    ushort* __restrict__ out,          // planar [8][N][32]
    const int* __restrict__ batch,
    float* __restrict__ sums,
    int M)
{
    __shared__ short Ls[2048 * 8];      // 32 KB

    constexpr int NCH1 = K1 / 8;        // 16 or 32
    constexpr int NSLOT1 = 64 * NCH1;   // 1024 or 2048
    constexpr int NS1 = K1 / 32;        // 4 or 8

    int t = threadIdx.x;
    int lane = t & 63;
    int wv = t >> 6;                    // 0..7
    int quad = lane >> 4;
    int l15 = lane & 15;
    int swz = l15 & 7;
    int row0 = blockIdx.x * 64;
    int col0 = wv * 32;

    // ---- Preload W1 slice into registers ----
    short8 bw[16];
    #pragma unroll
    for (int s = 0; s < NS1; ++s)
        #pragma unroll
        for (int j = 0; j < 2; ++j)
            bw[s * 2 + j] = *(const short8*)(w1t + (long)(col0 + j * 16 + l15) * K1 + s * 32 + quad * 8);

    float bv[2];
    #pragma unroll
    for (int j = 0; j < 2; ++j) bv[j] = b1[col0 + j * 16 + l15];

    // ---- Stage A tile (64 x K1, source-side swizzle) ----
    #pragma unroll
    for (int c = 0; c < NSLOT1; c += 512) {
        int s = c + t;
        int row = s / NCH1;
        int kcs = s & (NCH1 - 1);
        int kc = kcs ^ (row & 7);
        int grow = row0 + row;
        if (grow >= M) grow = M - 1;
        short8 v = *(const short8*)(A + (long)grow * K1 + kc * 8);
        *(short8*)&Ls[s * 8] = v;
    }
    __syncthreads();

    const f32x4 zero = {0.f, 0.f, 0.f, 0.f};
    f32x4 acc[4][2];
    #pragma unroll
    for (int i = 0; i < 4; ++i)
        #pragma unroll
        for (int j = 0; j < 2; ++j) acc[i][j] = zero;

    // ---- Layer 1: K-loop, LDS + registers only ----
    #pragma unroll
    for (int s = 0; s < NS1; ++s) {
        #pragma unroll
        for (int i = 0; i < 4; ++i) {
            int row = i * 16 + l15;
            int slot = row * NCH1 + ((s * 4 + quad) ^ swz);
            short8 a = *(const short8*)&Ls[slot * 8];
            acc[i][0] = __builtin_amdgcn_mfma_f32_16x16x32_bf16(a, bw[s * 2 + 0], acc[i][0], 0, 0, 0);
            acc[i][1] = __builtin_amdgcn_mfma_f32_16x16x32_bf16(a, bw[s * 2 + 1], acc[i][1], 0, 0, 0);
        }
    }

    // ---- Preload W2 slice (reuse bw regs); latency hides under barriers ----
    #pragma unroll
    for (int s = 0; s < 8; ++s)
        #pragma unroll
        for (int j = 0; j < 2; ++j)
            bw[s * 2 + j] = *(const short8*)(w2t + (long)(col0 + j * 16 + l15) * 256 + s * 32 + quad * 8);

    __syncthreads();

    // ---- H = relu(acc + b1) -> LDS (swizzled 64 x 256 bf16) ----
    #pragma unroll
    for (int i = 0; i < 4; ++i)
        #pragma unroll
        for (int j = 0; j < 2; ++j) {
            int col = col0 + j * 16 + l15;
            int kc2 = col >> 3, sub = col & 7;
            #pragma unroll
            for (int r = 0; r < 4; ++r) {
                int row = i * 16 + quad * 4 + r;
                int slot = row * 32 + (kc2 ^ (row & 7));
                float o = fmaxf(acc[i][j][r] + bv[j], 0.f);
                Ls[slot * 8 + sub] = (short)f2bf(o);
            }
        }

    #pragma unroll
    for (int j = 0; j < 2; ++j) bv[j] = b2[col0 + j * 16 + l15];

    __syncthreads();

    #pragma unroll
    for (int i = 0; i < 4; ++i)
        #pragma unroll
        for (int j = 0; j < 2; ++j) acc[i][j] = zero;

    // ---- Layer 2: K-loop, LDS + registers only ----
    #pragma unroll
    for (int s = 0; s < 8; ++s) {
        #pragma unroll
        for (int i = 0; i < 4; ++i) {
            int row = i * 16 + l15;
            int slot = row * 32 + ((s * 4 + quad) ^ swz);
            short8 a = *(const short8*)&Ls[slot * 8];
            acc[i][0] = __builtin_amdgcn_mfma_f32_16x16x32_bf16(a, bw[s * 2 + 0], acc[i][0], 0, 0, 0);
            acc[i][1] = __builtin_amdgcn_mfma_f32_16x16x32_bf16(a, bw[s * 2 + 1], acc[i][1], 0, 0, 0);
        }
    }

    if constexpr (!FUSE_POOL) {
        #pragma unroll
        for (int i = 0; i < 4; ++i)
            #pragma unroll
            for (int r = 0; r < 4; ++r) {
                int row = row0 + i * 16 + quad * 4 + r;
                if (row >= M) continue;
                #pragma unroll
                for (int j = 0; j < 2; ++j) {
                    int col = col0 + j * 16 + l15;
                    float o = fmaxf(acc[i][j][r] + bv[j], 0.f);
                    out[(long)(col >> 5) * PLANE_ELEMS + (long)row * 32 + (col & 31)] = f2bf(o);
                }
            }
    } else {
        float pacc[2];
        #pragma unroll
        for (int j = 0; j < 2; ++j) pacc[j] = 0.f;
        int cur = -1;
        #pragma unroll
        for (int i = 0; i < 4; ++i) {
            #pragma unroll
            for (int r = 0; r < 4; ++r) {
                int row = row0 + i * 16 + quad * 4 + r;
                if (row >= M) continue;
                int g = batch[row];
                if (g != cur) {
                    if (cur >= 0) {
                        #pragma unroll
                        for (int j = 0; j < 2; ++j)
                            atomicAdd(&sums[(long)cur * 256 + col0 + j * 16 + l15], pacc[j]);
                    }
                    cur = g;
                    #pragma unroll
                    for (int j = 0; j < 2; ++j) pacc[j] = 0.f;
                }
                #pragma unroll
                for (int j = 0; j < 2; ++j)
                    pacc[j] += fmaxf(acc[i][j][r] + bv[j], 0.f);
            }
        }
        if (cur >= 0) {
            #pragma unroll
            for (int j = 0; j < 2; ++j)
                atomicAdd(&sums[(long)cur * 256 + col0 + j * 16 + l15], pacc[j]);
        }
    }
}

// ===========================================================================
// Head MLP (fp32): one block per graph; count via binary search on batch.
// ===========================================================================
__global__ __launch_bounds__(256) void final_mlp_kernel(
    const float* __restrict__ sums, const int* __restrict__ batch,
    const float* __restrict__ w1, const float* __restrict__ b1,
    const float* __restrict__ w2, const float* __restrict__ b2,
    float* __restrict__ out) {
    __shared__ float row[HID];
    __shared__ float hid[HID];
    __shared__ int cntS;
    int g = blockIdx.x;
    int t = threadIdx.x;
    if (t == 0) {
        int lo = 0, hi = N_NODES;
        while (lo < hi) { int m = (lo + hi) >> 1; if (batch[m] < g) lo = m + 1; else hi = m; }
        int lo2 = lo, hi2 = N_NODES;
        while (lo2 < hi2) { int m = (lo2 + hi2) >> 1; if (batch[m] < g + 1) lo2 = m + 1; else hi2 = m; }
        cntS = lo2 - lo;
    }
    __syncthreads();
    float cnt = fmaxf((float)cntS, 1.0f);
    row[t] = sums[(long)g * HID + t] / cnt;
    __syncthreads();
    float acc = b1[t];
    for (int k = 0; k < HID; ++k) acc += row[k] * w1[k * HID + t];
    hid[t] = fmaxf(acc, 0.f);
    __syncthreads();
    if (t < OUT_C) {
        float o = b2[t];
        for (int k = 0; k < HID; ++k) o += hid[k] * w2[k * OUT_C + t];
        out[(long)g * OUT_C + t] = o;
    }
}

// ---------------------------------------------------------------------------
extern "C" void kernel_launch(void* const* d_in, const int* in_sizes, int n_in,
                              void* d_out, int out_size, void* d_ws, size_t ws_size,
                              hipStream_t stream) {
    const float* x     = (const float*)d_in[0];
    const int*   ei    = (const int*)d_in[1];
    const int*   batch = (const int*)d_in[2];
    const int*   src   = ei;
    const int*   dst   = ei + N_EDGES;

    const float* c_w1[3] = { (const float*)d_in[3],  (const float*)d_in[7],  (const float*)d_in[11] };
    const float* c_b1[3] = { (const float*)d_in[4],  (const float*)d_in[8],  (const float*)d_in[12] };
    const float* c_w2[3] = { (const float*)d_in[5],  (const float*)d_in[9],  (const float*)d_in[13] };
    const float* c_b2[3] = { (const float*)d_in[6],  (const float*)d_in[10], (const float*)d_in[14] };
    const float* out_w1 = (const float*)d_in[15];
    const float* out_b1 = (const float*)d_in[16];
    const float* out_w2 = (const float*)d_in[17];
    const float* out_b2 = (const float*)d_in[18];

    // ---- Workspace layout (16B aligned) ----
    char* p = (char*)d_ws;
    auto alloc = [&](size_t bytes) {
        char* r = p;
        p += (bytes + 15) & ~(size_t)15;
        return r;
    };
    ushort* xbf  = (ushort*)alloc((size_t)N_NODES * IN_C * 2);   // planar [4][N][32]
    ushort* bufA = (ushort*)alloc((size_t)N_NODES * HID * 2);    // planar [8][N][32]
    ushort* bufB = (ushort*)alloc((size_t)N_NODES * HID * 2);    // row-major agg output
    ushort* wt[6];
    wt[0] = (ushort*)alloc((size_t)IN_C * HID * 2);
    for (int i = 1; i < 6; ++i) wt[i] = (ushort*)alloc((size_t)HID * HID * 2);
    float* sums   = (float*)alloc((size_t)N_GRAPHS * HID * 4);
    int* deg       = (int*)alloc((size_t)N_NODES * 4);
    int* rowptr    = (int*)alloc((size_t)(N_NODES + 1) * 4);
    int* blockSums = (int*)alloc(256 * 4);
    int* cursor    = (int*)alloc((size_t)N_NODES * 4);
    int* srcSorted = (int*)alloc((size_t)N_EDGES * 4);

    const int nb = (N_NODES + 255) / 256;

    // ---- Prep: one dispatch for casts + transposes + zeroing ----
    {
        PrepArgs a;
        a.x = x;
        a.w[0] = c_w1[0]; a.w[1] = c_w2[0];
        a.w[2] = c_w1[1]; a.w[3] = c_w2[1];
        a.w[4] = c_w1[2]; a.w[5] = c_w2[2];
        a.xbf = xbf;
        for (int i = 0; i < 6; ++i) a.wt[i] = wt[i];
        a.deg = deg;
        a.sums = sums;
        prep_kernel<<<2048, 256, 0, stream>>>(a);
    }

    // ---- Build CSR by dst ----
    deg_kernel<<<(N_EDGES + 255) / 256, 256, 0, stream>>>(dst, deg);
    scan_block<<<nb, 256, 0, stream>>>(deg, rowptr, blockSums);
    add_offsets_fused<<<nb, 256, 0, stream>>>(rowptr, blockSums, rowptr, cursor, nb);
    bucket_edges<<<(N_EDGES + 255) / 256, 256, 0, stream>>>(src, dst, cursor, srcSorted);

    const int nodeBlks = (N_NODES + 63) / 64;        // 782 (even, needed for PER=2)
    const int aggX128  = nodeBlks * (IN_C / 32);     // 3128
    const int aggX256  = nodeBlks * (HID / 32);      // 6256
    const int mlpGrid  = (N_NODES + 63) / 64;        // 782

    // ---- Layer 0 (C_in = 128) ----
    gin_aggregate_planar<IN_C><<<aggX128, 256, 0, stream>>>(xbf, rowptr, srcSorted, bufB);
    gin_mlp<IN_C, false><<<mlpGrid, 512, 0, stream>>>(bufB, wt[0], c_b1[0], wt[1], c_b2[0],
                                                      bufA, batch, sums, N_NODES);

    // ---- Layer 1 (C = 256) ----
    gin_aggregate_planar<HID><<<aggX256, 256, 0, stream>>>(bufA, rowptr, srcSorted, bufB);
    gin_mlp<HID, false><<<mlpGrid, 512, 0, stream>>>(bufB, wt[2], c_b1[1], wt[3], c_b2[1],
                                                     bufA, batch, sums, N_NODES);

    // ---- Layer 2 (C = 256) with fused global mean-pool accumulation ----
    gin_aggregate_planar<HID><<<aggX256, 256, 0, stream>>>(bufA, rowptr, srcSorted, bufB);
    gin_mlp<HID, true><<<mlpGrid, 512, 0, stream>>>(bufB, wt[4], c_b1[2], wt[5], c_b2[2],
                                                    bufA, batch, sums, N_NODES);

    // ---- Head MLP ----
    final_mlp_kernel<<<N_GRAPHS, 256, 0, stream>>>(sums, batch, out_w1, out_b1,
                                                   out_w2, out_b2, (float*)d_out);
}

// Round 6
// 444.612 us; speedup vs baseline: 1.3712x; 1.1853x over previous
//
#include <hip/hip_runtime.h>

#define N_NODES 50000
#define N_EDGES 800000
#define N_GRAPHS 512
#define IN_C 128
#define HID 256
#define OUT_C 16

typedef __attribute__((ext_vector_type(8))) short short8;
typedef __attribute__((ext_vector_type(4))) float f32x4;

__device__ __forceinline__ float bf2f(unsigned short u) {
    return __uint_as_float(((unsigned int)u) << 16);
}
__device__ __forceinline__ unsigned short f2bf(float f) {
    unsigned int u = __float_as_uint(f);
    u += 0x7fff + ((u >> 16) & 1);   // RNE
    return (unsigned short)(u >> 16);
}

// Planar layout: features stored as [C/32 planes][N_NODES][32 cols] bf16.
// Each plane is 50000*64B = 3.2 MB (contiguous) -> fits one XCD's 4 MB L2.
#define PLANE_ELEMS ((long)N_NODES * 32)

// ===========================================================================
// Prep (single dispatch): x -> bf16 PLANAR, six weight transposes (K x 256
// fp32 -> 256 x K bf16), zero deg, zero sums.
// ===========================================================================
struct PrepArgs {
    const float* x;
    const float* w[6];      // K x 256 row-major; K = 128 for w[0], else 256
    ushort* xbf;            // planar [4][N][32]
    ushort* wt[6];
    int* deg;
    float* sums;
};

__global__ __launch_bounds__(256) void prep_kernel(PrepArgs a) {
    const int X4    = N_NODES * IN_C / 4;
    const int TW    = IN_C * HID;
    const int TH    = HID * HID;
    const int TBASE = X4;
    const int TEND  = TBASE + TW + 5 * TH;
    const int D4    = N_NODES / 4;
    const int DBASE = TEND;
    const int SBASE = DBASE + D4;
    const int S4    = N_GRAPHS * HID / 4;
    const long total = (long)SBASE + S4;

    long stride = (long)gridDim.x * blockDim.x;
    for (long i = (long)blockIdx.x * blockDim.x + threadIdx.x; i < total; i += stride) {
        if (i < X4) {
            float4 v = ((const float4*)a.x)[i];
            ushort4 o;
            o.x = f2bf(v.x); o.y = f2bf(v.y); o.z = f2bf(v.z); o.w = f2bf(v.w);
            long e = i * 4;
            int node = (int)(e >> 7);         // /128
            int col  = (int)(e & 127);
            long off = (long)(col >> 5) * PLANE_ELEMS + (long)node * 32 + (col & 31);
            *(ushort4*)(a.xbf + off) = o;
        } else if (i < TEND) {
            long r = i - TBASE;
            int wi, shift;
            long off;
            if (r < TW) { wi = 0; shift = 7; off = r; }
            else { r -= TW; wi = 1 + (int)(r / TH); shift = 8; off = r % TH; }
            int n = (int)(off >> shift);
            int k = (int)(off - ((long)n << shift));
            a.wt[wi][off] = f2bf(a.w[wi][(long)k * HID + n]);
        } else if (i < SBASE) {
            ((int4*)a.deg)[i - DBASE] = make_int4(0, 0, 0, 0);
        } else {
            ((float4*)a.sums)[i - SBASE] = make_float4(0.f, 0.f, 0.f, 0.f);
        }
    }
}

// ===========================================================================
// CSR build: deg histogram -> scan (2 fused dispatches) -> bucket by dst.
// ===========================================================================
__global__ void deg_kernel(const int* __restrict__ dst, int* __restrict__ deg) {
    int e = blockIdx.x * blockDim.x + threadIdx.x;
    if (e < N_EDGES) atomicAdd(&deg[dst[e]], 1);
}

__global__ __launch_bounds__(256) void scan_block(const int* __restrict__ deg,
                                                  int* __restrict__ partial,
                                                  int* __restrict__ blockSums) {
    __shared__ int s[256];
    int t = threadIdx.x;
    int i = blockIdx.x * 256 + t;
    int v = (i < N_NODES) ? deg[i] : 0;
    s[t] = v;
    __syncthreads();
    #pragma unroll
    for (int off = 1; off < 256; off <<= 1) {
        int add = (t >= off) ? s[t - off] : 0;
        __syncthreads();
        s[t] += add;
        __syncthreads();
    }
    if (i < N_NODES) partial[i] = s[t] - v;
    if (t == 255) blockSums[blockIdx.x] = s[255];
}

__global__ __launch_bounds__(256) void add_offsets_fused(
    const int* __restrict__ partial, const int* __restrict__ blockSums,
    int* __restrict__ rowptr, int* __restrict__ cursor, int nb) {
    __shared__ int s[256];
    __shared__ int myOff;
    int t = threadIdx.x;
    int v = (t < nb) ? blockSums[t] : 0;
    s[t] = v;
    __syncthreads();
    #pragma unroll
    for (int off = 1; off < 256; off <<= 1) {
        int add = (t >= off) ? s[t - off] : 0;
        __syncthreads();
        s[t] += add;
        __syncthreads();
    }
    if (t == blockIdx.x) myOff = s[t] - v;
    __syncthreads();
    int i = blockIdx.x * 256 + t;
    if (i < N_NODES) {
        int r = partial[i] + myOff;
        rowptr[i] = r;
        cursor[i] = r;
    }
    if (i == 0) rowptr[N_NODES] = N_EDGES;
}

__global__ void bucket_edges(const int* __restrict__ src, const int* __restrict__ dst,
                             int* __restrict__ cursor, int* __restrict__ srcSorted) {
    int e = blockIdx.x * blockDim.x + threadIdx.x;
    if (e >= N_EDGES) return;
    int p = atomicAdd(&cursor[dst[e]], 1);
    srcSorted[p] = src[e];
}

// ===========================================================================
// Aggregation, planar-in / row-major-out: out[n] = h[n] + sum h[src].
//
// Index/rowptr loads: NORMAL cached (R5 lesson: nt loads on the address-
// generation chain are poison). Output stores: non-temporal so the 25.6 MB
// write stream does not allocate in L2 and evict the resident plane.
// ===========================================================================
template <int C>
__global__ __launch_bounds__(256) void gin_aggregate_planar(
    const ushort* __restrict__ hp,     // planar [C/32][N][32]
    const int* __restrict__ rowptr,
    const int* __restrict__ srcIdx,
    ushort* __restrict__ out)          // row-major [N][C]
{
    constexpr int NC  = C / 32;        // 4 (C=128) or 8 (C=256)
    constexpr int PER = 8 / NC;        // XCDs per plane (2 or 1)

    int b  = blockIdx.x;
    int x8 = b & 7;                    // presumed XCD id (round-robin)
    int chunk   = x8 / PER;
    int nodeblk = (b >> 3) * PER + (x8 & (PER - 1));

    int lane = threadIdx.x & 63;
    int wave = threadIdx.x >> 6;
    int grp  = lane >> 2;              // 0..15: node within wave
    int l    = lane & 3;               // 4 lanes x 8 bf16 = 32 cols
    int node = nodeblk * 64 + wave * 16 + grp;
    if (node >= N_NODES) return;

    const ushort* plane = hp + (long)chunk * PLANE_ELEMS + l * 8;

    float acc[8];
    {
        short8 sv = *(const short8*)(plane + (long)node * 32);
        #pragma unroll
        for (int v = 0; v < 8; ++v) acc[v] = bf2f((unsigned short)sv[v]);
    }

    int beg = rowptr[node], end = rowptr[node + 1];
    int k = beg;
    for (; k + 8 <= end; k += 8) {
        int si[8];
        #pragma unroll
        for (int u = 0; u < 8; ++u) si[u] = srcIdx[k + u];
        short8 r[8];
        #pragma unroll
        for (int u = 0; u < 8; ++u) r[u] = *(const short8*)(plane + (long)si[u] * 32);
        #pragma unroll
        for (int u = 0; u < 8; ++u)
            #pragma unroll
            for (int v = 0; v < 8; ++v) acc[v] += bf2f((unsigned short)r[u][v]);
    }
    for (; k + 2 <= end; k += 2) {
        int si0 = srcIdx[k], si1 = srcIdx[k + 1];
        short8 r0 = *(const short8*)(plane + (long)si0 * 32);
        short8 r1 = *(const short8*)(plane + (long)si1 * 32);
        #pragma unroll
        for (int v = 0; v < 8; ++v) acc[v] += bf2f((unsigned short)r0[v]);
        #pragma unroll
        for (int v = 0; v < 8; ++v) acc[v] += bf2f((unsigned short)r1[v]);
    }
    if (k < end) {
        short8 r = *(const short8*)(plane + (long)srcIdx[k] * 32);
        #pragma unroll
        for (int v = 0; v < 8; ++v) acc[v] += bf2f((unsigned short)r[v]);
    }

    short8 o;
    #pragma unroll
    for (int v = 0; v < 8; ++v) o[v] = (short)f2bf(acc[v]);
    __builtin_nontemporal_store(o, (short8*)(out + (long)node * C + chunk * 32 + l * 8));
}

// ===========================================================================
// Fused 2-layer MLP, weights-in-registers. Epilogue (!FUSE_POOL) now bounces
// the output tile through LDS so the planar global write is 4x 16B coalesced
// stores per thread instead of 32x 2B scattered stores.
// LDS: max(staging 32KB, epilogue 64 x 272 shorts = 34.8KB).
// ===========================================================================
template <int K1, bool FUSE_POOL>
__global__ __launch_bounds__(512, 4) void gin_mlp(
    const ushort* __restrict__ A,
    const ushort* __restrict__ w1t,
    const float* __restrict__ b1,
    const ushort* __restrict__ w2t,
    const float* __restrict__ b2,
    ushort* __restrict__ out,          // planar [8][N][32]
    const int* __restrict__ batch,
    float* __restrict__ sums,
    int M)
{
    __shared__ short Ls[17408];         // 34.8 KB (>= 2048*8 staging)

    constexpr int NCH1 = K1 / 8;        // 16 or 32
    constexpr int NSLOT1 = 64 * NCH1;   // 1024 or 2048
    constexpr int NS1 = K1 / 32;        // 4 or 8

    int t = threadIdx.x;
    int lane = t & 63;
    int wv = t >> 6;                    // 0..7
    int quad = lane >> 4;
    int l15 = lane & 15;
    int swz = l15 & 7;
    int row0 = blockIdx.x * 64;
    int col0 = wv * 32;

    // ---- Preload W1 slice into registers ----
    short8 bw[16];
    #pragma unroll
    for (int s = 0; s < NS1; ++s)
        #pragma unroll
        for (int j = 0; j < 2; ++j)
            bw[s * 2 + j] = *(const short8*)(w1t + (long)(col0 + j * 16 + l15) * K1 + s * 32 + quad * 8);

    float bv[2];
    #pragma unroll
    for (int j = 0; j < 2; ++j) bv[j] = b1[col0 + j * 16 + l15];

    // ---- Stage A tile (64 x K1, source-side swizzle) ----
    #pragma unroll
    for (int c = 0; c < NSLOT1; c += 512) {
        int s = c + t;
        int row = s / NCH1;
        int kcs = s & (NCH1 - 1);
        int kc = kcs ^ (row & 7);
        int grow = row0 + row;
        if (grow >= M) grow = M - 1;
        short8 v = *(const short8*)(A + (long)grow * K1 + kc * 8);
        *(short8*)&Ls[s * 8] = v;
    }
    __syncthreads();

    const f32x4 zero = {0.f, 0.f, 0.f, 0.f};
    f32x4 acc[4][2];
    #pragma unroll
    for (int i = 0; i < 4; ++i)
        #pragma unroll
        for (int j = 0; j < 2; ++j) acc[i][j] = zero;

    // ---- Layer 1: K-loop, LDS + registers only ----
    #pragma unroll
    for (int s = 0; s < NS1; ++s) {
        #pragma unroll
        for (int i = 0; i < 4; ++i) {
            int row = i * 16 + l15;
            int slot = row * NCH1 + ((s * 4 + quad) ^ swz);
            short8 a = *(const short8*)&Ls[slot * 8];
            acc[i][0] = __builtin_amdgcn_mfma_f32_16x16x32_bf16(a, bw[s * 2 + 0], acc[i][0], 0, 0, 0);
            acc[i][1] = __builtin_amdgcn_mfma_f32_16x16x32_bf16(a, bw[s * 2 + 1], acc[i][1], 0, 0, 0);
        }
    }

    // ---- Preload W2 slice (reuse bw regs); latency hides under barriers ----
    #pragma unroll
    for (int s = 0; s < 8; ++s)
        #pragma unroll
        for (int j = 0; j < 2; ++j)
            bw[s * 2 + j] = *(const short8*)(w2t + (long)(col0 + j * 16 + l15) * 256 + s * 32 + quad * 8);

    __syncthreads();

    // ---- H = relu(acc + b1) -> LDS (swizzled 64 x 256 bf16) ----
    #pragma unroll
    for (int i = 0; i < 4; ++i)
        #pragma unroll
        for (int j = 0; j < 2; ++j) {
            int col = col0 + j * 16 + l15;
            int kc2 = col >> 3, sub = col & 7;
            #pragma unroll
            for (int r = 0; r < 4; ++r) {
                int row = i * 16 + quad * 4 + r;
                int slot = row * 32 + (kc2 ^ (row & 7));
                float o = fmaxf(acc[i][j][r] + bv[j], 0.f);
                Ls[slot * 8 + sub] = (short)f2bf(o);
            }
        }

    #pragma unroll
    for (int j = 0; j < 2; ++j) bv[j] = b2[col0 + j * 16 + l15];

    __syncthreads();

    #pragma unroll
    for (int i = 0; i < 4; ++i)
        #pragma unroll
        for (int j = 0; j < 2; ++j) acc[i][j] = zero;

    // ---- Layer 2: K-loop, LDS + registers only ----
    #pragma unroll
    for (int s = 0; s < 8; ++s) {
        #pragma unroll
        for (int i = 0; i < 4; ++i) {
            int row = i * 16 + l15;
            int slot = row * 32 + ((s * 4 + quad) ^ swz);
            short8 a = *(const short8*)&Ls[slot * 8];
            acc[i][0] = __builtin_amdgcn_mfma_f32_16x16x32_bf16(a, bw[s * 2 + 0], acc[i][0], 0, 0, 0);
            acc[i][1] = __builtin_amdgcn_mfma_f32_16x16x32_bf16(a, bw[s * 2 + 1], acc[i][1], 0, 0, 0);
        }
    }

    if constexpr (!FUSE_POOL) {
        // ---- Epilogue via LDS bounce: coalesced planar stores ----
        __syncthreads();                 // done reading H from Ls
        #pragma unroll
        for (int i = 0; i < 4; ++i)
            #pragma unroll
            for (int j = 0; j < 2; ++j) {
                int col = col0 + j * 16 + l15;
                #pragma unroll
                for (int r = 0; r < 4; ++r) {
                    int row = i * 16 + quad * 4 + r;
                    float o = fmaxf(acc[i][j][r] + bv[j], 0.f);
                    Ls[row * 272 + col] = (short)f2bf(o);
                }
            }
        __syncthreads();
        #pragma unroll
        for (int k = 0; k < 4; ++k) {
            int piece = t + k * 512;     // 2048 pieces = 8 chunks x 64 rows x 4
            int chunk = piece >> 8;
            int wc    = piece & 255;
            int row   = wc >> 2;
            int g     = wc & 3;
            int grow  = row0 + row;
            if (grow < M) {
                short8 v = *(const short8*)&Ls[row * 272 + chunk * 32 + g * 8];
                *(short8*)(out + (long)chunk * PLANE_ELEMS + (long)grow * 32 + g * 8) = v;
            }
        }
    } else {
        float pacc[2];
        #pragma unroll
        for (int j = 0; j < 2; ++j) pacc[j] = 0.f;
        int cur = -1;
        #pragma unroll
        for (int i = 0; i < 4; ++i) {
            #pragma unroll
            for (int r = 0; r < 4; ++r) {
                int row = row0 + i * 16 + quad * 4 + r;
                if (row >= M) continue;
                int g = batch[row];
                if (g != cur) {
                    if (cur >= 0) {
                        #pragma unroll
                        for (int j = 0; j < 2; ++j)
                            atomicAdd(&sums[(long)cur * 256 + col0 + j * 16 + l15], pacc[j]);
                    }
                    cur = g;
                    #pragma unroll
                    for (int j = 0; j < 2; ++j) pacc[j] = 0.f;
                }
                #pragma unroll
                for (int j = 0; j < 2; ++j)
                    pacc[j] += fmaxf(acc[i][j][r] + bv[j], 0.f);
            }
        }
        if (cur >= 0) {
            #pragma unroll
            for (int j = 0; j < 2; ++j)
                atomicAdd(&sums[(long)cur * 256 + col0 + j * 16 + l15], pacc[j]);
        }
    }
}

// ===========================================================================
// Head MLP (fp32): one block per graph; count via binary search on batch.
// ===========================================================================
__global__ __launch_bounds__(256) void final_mlp_kernel(
    const float* __restrict__ sums, const int* __restrict__ batch,
    const float* __restrict__ w1, const float* __restrict__ b1,
    const float* __restrict__ w2, const float* __restrict__ b2,
    float* __restrict__ out) {
    __shared__ float row[HID];
    __shared__ float hid[HID];
    __shared__ int cntS;
    int g = blockIdx.x;
    int t = threadIdx.x;
    if (t == 0) {
        int lo = 0, hi = N_NODES;
        while (lo < hi) { int m = (lo + hi) >> 1; if (batch[m] < g) lo = m + 1; else hi = m; }
        int lo2 = lo, hi2 = N_NODES;
        while (lo2 < hi2) { int m = (lo2 + hi2) >> 1; if (batch[m] < g + 1) lo2 = m + 1; else hi2 = m; }
        cntS = lo2 - lo;
    }
    __syncthreads();
    float cnt = fmaxf((float)cntS, 1.0f);
    row[t] = sums[(long)g * HID + t] / cnt;
    __syncthreads();
    float acc = b1[t];
    for (int k = 0; k < HID; ++k) acc += row[k] * w1[k * HID + t];
    hid[t] = fmaxf(acc, 0.f);
    __syncthreads();
    if (t < OUT_C) {
        float o = b2[t];
        for (int k = 0; k < HID; ++k) o += hid[k] * w2[k * OUT_C + t];
        out[(long)g * OUT_C + t] = o;
    }
}

// ---------------------------------------------------------------------------
extern "C" void kernel_launch(void* const* d_in, const int* in_sizes, int n_in,
                              void* d_out, int out_size, void* d_ws, size_t ws_size,
                              hipStream_t stream) {
    const float* x     = (const float*)d_in[0];
    const int*   ei    = (const int*)d_in[1];
    const int*   batch = (const int*)d_in[2];
    const int*   src   = ei;
    const int*   dst   = ei + N_EDGES;

    const float* c_w1[3] = { (const float*)d_in[3],  (const float*)d_in[7],  (const float*)d_in[11] };
    const float* c_b1[3] = { (const float*)d_in[4],  (const float*)d_in[8],  (const float*)d_in[12] };
    const float* c_w2[3] = { (const float*)d_in[5],  (const float*)d_in[9],  (const float*)d_in[13] };
    const float* c_b2[3] = { (const float*)d_in[6],  (const float*)d_in[10], (const float*)d_in[14] };
    const float* out_w1 = (const float*)d_in[15];
    const float* out_b1 = (const float*)d_in[16];
    const float* out_w2 = (const float*)d_in[17];
    const float* out_b2 = (const float*)d_in[18];

    // ---- Workspace layout (16B aligned) ----
    char* p = (char*)d_ws;
    auto alloc = [&](size_t bytes) {
        char* r = p;
        p += (bytes + 15) & ~(size_t)15;
        return r;
    };
    ushort* xbf  = (ushort*)alloc((size_t)N_NODES * IN_C * 2);   // planar [4][N][32]
    ushort* bufA = (ushort*)alloc((size_t)N_NODES * HID * 2);    // planar [8][N][32]
    ushort* bufB = (ushort*)alloc((size_t)N_NODES * HID * 2);    // row-major agg output
    ushort* wt[6];
    wt[0] = (ushort*)alloc((size_t)IN_C * HID * 2);
    for (int i = 1; i < 6; ++i) wt[i] = (ushort*)alloc((size_t)HID * HID * 2);
    float* sums   = (float*)alloc((size_t)N_GRAPHS * HID * 4);
    int* deg       = (int*)alloc((size_t)N_NODES * 4);
    int* rowptr    = (int*)alloc((size_t)(N_NODES + 1) * 4);
    int* blockSums = (int*)alloc(256 * 4);
    int* cursor    = (int*)alloc((size_t)N_NODES * 4);
    int* srcSorted = (int*)alloc((size_t)N_EDGES * 4);

    const int nb = (N_NODES + 255) / 256;

    // ---- Prep: one dispatch for casts + transposes + zeroing ----
    {
        PrepArgs a;
        a.x = x;
        a.w[0] = c_w1[0]; a.w[1] = c_w2[0];
        a.w[2] = c_w1[1]; a.w[3] = c_w2[1];
        a.w[4] = c_w1[2]; a.w[5] = c_w2[2];
        a.xbf = xbf;
        for (int i = 0; i < 6; ++i) a.wt[i] = wt[i];
        a.deg = deg;
        a.sums = sums;
        prep_kernel<<<2048, 256, 0, stream>>>(a);
    }

    // ---- Build CSR by dst ----
    deg_kernel<<<(N_EDGES + 255) / 256, 256, 0, stream>>>(dst, deg);
    scan_block<<<nb, 256, 0, stream>>>(deg, rowptr, blockSums);
    add_offsets_fused<<<nb, 256, 0, stream>>>(rowptr, blockSums, rowptr, cursor, nb);
    bucket_edges<<<(N_EDGES + 255) / 256, 256, 0, stream>>>(src, dst, cursor, srcSorted);

    const int nodeBlks = (N_NODES + 63) / 64;        // 782 (even, needed for PER=2)
    const int aggX128  = nodeBlks * (IN_C / 32);     // 3128
    const int aggX256  = nodeBlks * (HID / 32);      // 6256
    const int mlpGrid  = (N_NODES + 63) / 64;        // 782

    // ---- Layer 0 (C_in = 128) ----
    gin_aggregate_planar<IN_C><<<aggX128, 256, 0, stream>>>(xbf, rowptr, srcSorted, bufB);
    gin_mlp<IN_C, false><<<mlpGrid, 512, 0, stream>>>(bufB, wt[0], c_b1[0], wt[1], c_b2[0],
                                                      bufA, batch, sums, N_NODES);

    // ---- Layer 1 (C = 256) ----
    gin_aggregate_planar<HID><<<aggX256, 256, 0, stream>>>(bufA, rowptr, srcSorted, bufB);
    gin_mlp<HID, false><<<mlpGrid, 512, 0, stream>>>(bufB, wt[2], c_b1[1], wt[3], c_b2[1],
                                                     bufA, batch, sums, N_NODES);

    // ---- Layer 2 (C = 256) with fused global mean-pool accumulation ----
    gin_aggregate_planar<HID><<<aggX256, 256, 0, stream>>>(bufA, rowptr, srcSorted, bufB);
    gin_mlp<HID, true><<<mlpGrid, 512, 0, stream>>>(bufB, wt[4], c_b1[2], wt[5], c_b2[2],
                                                    bufA, batch, sums, N_NODES);

    // ---- Head MLP ----
    final_mlp_kernel<<<N_GRAPHS, 256, 0, stream>>>(sums, batch, out_w1, out_b1,
                                                   out_w2, out_b2, (float*)d_out);
}

// Round 7
// 432.694 us; speedup vs baseline: 1.4090x; 1.0275x over previous
//
#include <hip/hip_runtime.h>

#define N_NODES 50000
#define N_EDGES 800000
#define N_GRAPHS 512
#define IN_C 128
#define HID 256
#define OUT_C 16

typedef __attribute__((ext_vector_type(8))) short short8;
typedef __attribute__((ext_vector_type(4))) float f32x4;

__device__ __forceinline__ float bf2f(unsigned short u) {
    return __uint_as_float(((unsigned int)u) << 16);
}
__device__ __forceinline__ unsigned short f2bf(float f) {
    unsigned int u = __float_as_uint(f);
    u += 0x7fff + ((u >> 16) & 1);   // RNE
    return (unsigned short)(u >> 16);
}

// Planar layout: features stored as [C/32 planes][N_NODES][32 cols] bf16.
// Each plane is 50000*64B = 3.2 MB (contiguous) -> fits one XCD's 4 MB L2.
#define PLANE_ELEMS ((long)N_NODES * 32)

// ===========================================================================
// Prep (single dispatch): x -> bf16 PLANAR, six weight transposes (K x 256
// fp32 -> 256 x K bf16), zero deg, zero sums.
// ===========================================================================
struct PrepArgs {
    const float* x;
    const float* w[6];      // K x 256 row-major; K = 128 for w[0], else 256
    ushort* xbf;            // planar [4][N][32]
    ushort* wt[6];
    int* deg;
    float* sums;
};

__global__ __launch_bounds__(256) void prep_kernel(PrepArgs a) {
    const int X4    = N_NODES * IN_C / 4;
    const int TW    = IN_C * HID;
    const int TH    = HID * HID;
    const int TBASE = X4;
    const int TEND  = TBASE + TW + 5 * TH;
    const int D4    = N_NODES / 4;
    const int DBASE = TEND;
    const int SBASE = DBASE + D4;
    const int S4    = N_GRAPHS * HID / 4;
    const long total = (long)SBASE + S4;

    long stride = (long)gridDim.x * blockDim.x;
    for (long i = (long)blockIdx.x * blockDim.x + threadIdx.x; i < total; i += stride) {
        if (i < X4) {
            float4 v = ((const float4*)a.x)[i];
            ushort4 o;
            o.x = f2bf(v.x); o.y = f2bf(v.y); o.z = f2bf(v.z); o.w = f2bf(v.w);
            long e = i * 4;
            int node = (int)(e >> 7);         // /128
            int col  = (int)(e & 127);
            long off = (long)(col >> 5) * PLANE_ELEMS + (long)node * 32 + (col & 31);
            *(ushort4*)(a.xbf + off) = o;
        } else if (i < TEND) {
            long r = i - TBASE;
            int wi, shift;
            long off;
            if (r < TW) { wi = 0; shift = 7; off = r; }
            else { r -= TW; wi = 1 + (int)(r / TH); shift = 8; off = r % TH; }
            int n = (int)(off >> shift);
            int k = (int)(off - ((long)n << shift));
            a.wt[wi][off] = f2bf(a.w[wi][(long)k * HID + n]);
        } else if (i < SBASE) {
            ((int4*)a.deg)[i - DBASE] = make_int4(0, 0, 0, 0);
        } else {
            ((float4*)a.sums)[i - SBASE] = make_float4(0.f, 0.f, 0.f, 0.f);
        }
    }
}

// ===========================================================================
// CSR build: deg histogram -> scan (2 fused dispatches) -> bucket by dst.
// ===========================================================================
__global__ void deg_kernel(const int* __restrict__ dst, int* __restrict__ deg) {
    int e = blockIdx.x * blockDim.x + threadIdx.x;
    if (e < N_EDGES) atomicAdd(&deg[dst[e]], 1);
}

__global__ __launch_bounds__(256) void scan_block(const int* __restrict__ deg,
                                                  int* __restrict__ partial,
                                                  int* __restrict__ blockSums) {
    __shared__ int s[256];
    int t = threadIdx.x;
    int i = blockIdx.x * 256 + t;
    int v = (i < N_NODES) ? deg[i] : 0;
    s[t] = v;
    __syncthreads();
    #pragma unroll
    for (int off = 1; off < 256; off <<= 1) {
        int add = (t >= off) ? s[t - off] : 0;
        __syncthreads();
        s[t] += add;
        __syncthreads();
    }
    if (i < N_NODES) partial[i] = s[t] - v;
    if (t == 255) blockSums[blockIdx.x] = s[255];
}

__global__ __launch_bounds__(256) void add_offsets_fused(
    const int* __restrict__ partial, const int* __restrict__ blockSums,
    int* __restrict__ rowptr, int* __restrict__ cursor, int nb) {
    __shared__ int s[256];
    __shared__ int myOff;
    int t = threadIdx.x;
    int v = (t < nb) ? blockSums[t] : 0;
    s[t] = v;
    __syncthreads();
    #pragma unroll
    for (int off = 1; off < 256; off <<= 1) {
        int add = (t >= off) ? s[t - off] : 0;
        __syncthreads();
        s[t] += add;
        __syncthreads();
    }
    if (t == blockIdx.x) myOff = s[t] - v;
    __syncthreads();
    int i = blockIdx.x * 256 + t;
    if (i < N_NODES) {
        int r = partial[i] + myOff;
        rowptr[i] = r;
        cursor[i] = r;
    }
    if (i == 0) rowptr[N_NODES] = N_EDGES;
}

__global__ void bucket_edges(const int* __restrict__ src, const int* __restrict__ dst,
                             int* __restrict__ cursor, int* __restrict__ srcSorted) {
    int e = blockIdx.x * blockDim.x + threadIdx.x;
    if (e >= N_EDGES) return;
    int p = atomicAdd(&cursor[dst[e]], 1);
    __builtin_nontemporal_store(src[e], &srcSorted[p]);
}

// ===========================================================================
// Aggregation, planar-in / row-major-out: out[n] = h[n] + sum h[src].
// Cached index loads, nt output stores (round-6: dropped out of top-5).
// ===========================================================================
template <int C>
__global__ __launch_bounds__(256) void gin_aggregate_planar(
    const ushort* __restrict__ hp,     // planar [C/32][N][32]
    const int* __restrict__ rowptr,
    const int* __restrict__ srcIdx,
    ushort* __restrict__ out)          // row-major [N][C]
{
    constexpr int NC  = C / 32;        // 4 (C=128) or 8 (C=256)
    constexpr int PER = 8 / NC;        // XCDs per plane (2 or 1)

    int b  = blockIdx.x;
    int x8 = b & 7;                    // presumed XCD id (round-robin)
    int chunk   = x8 / PER;
    int nodeblk = (b >> 3) * PER + (x8 & (PER - 1));

    int lane = threadIdx.x & 63;
    int wave = threadIdx.x >> 6;
    int grp  = lane >> 2;              // 0..15: node within wave
    int l    = lane & 3;               // 4 lanes x 8 bf16 = 32 cols
    int node = nodeblk * 64 + wave * 16 + grp;
    if (node >= N_NODES) return;

    const ushort* plane = hp + (long)chunk * PLANE_ELEMS + l * 8;

    float acc[8];
    {
        short8 sv = *(const short8*)(plane + (long)node * 32);
        #pragma unroll
        for (int v = 0; v < 8; ++v) acc[v] = bf2f((unsigned short)sv[v]);
    }

    int beg = rowptr[node], end = rowptr[node + 1];
    int k = beg;
    for (; k + 8 <= end; k += 8) {
        int si[8];
        #pragma unroll
        for (int u = 0; u < 8; ++u) si[u] = srcIdx[k + u];
        short8 r[8];
        #pragma unroll
        for (int u = 0; u < 8; ++u) r[u] = *(const short8*)(plane + (long)si[u] * 32);
        #pragma unroll
        for (int u = 0; u < 8; ++u)
            #pragma unroll
            for (int v = 0; v < 8; ++v) acc[v] += bf2f((unsigned short)r[u][v]);
    }
    for (; k + 2 <= end; k += 2) {
        int si0 = srcIdx[k], si1 = srcIdx[k + 1];
        short8 r0 = *(const short8*)(plane + (long)si0 * 32);
        short8 r1 = *(const short8*)(plane + (long)si1 * 32);
        #pragma unroll
        for (int v = 0; v < 8; ++v) acc[v] += bf2f((unsigned short)r0[v]);
        #pragma unroll
        for (int v = 0; v < 8; ++v) acc[v] += bf2f((unsigned short)r1[v]);
    }
    if (k < end) {
        short8 r = *(const short8*)(plane + (long)srcIdx[k] * 32);
        #pragma unroll
        for (int v = 0; v < 8; ++v) acc[v] += bf2f((unsigned short)r[v]);
    }

    short8 o;
    #pragma unroll
    for (int v = 0; v < 8; ++v) o[v] = (short)f2bf(acc[v]);
    __builtin_nontemporal_store(o, (short8*)(out + (long)node * C + chunk * 32 + l * 8));
}

// ===========================================================================
// PERSISTENT fused 2-layer MLP. Grid = 256 blocks (1/CU); each block:
//  - preloads its W1+W2 column slices (+biases) into registers ONCE,
//  - loops over a contiguous range of 64-row tiles with the 3-barrier phase
//    structure. LsA (A-stage) and LsH (intermediate H) are separate buffers
//    so per-tile phases never alias across iterations.
// Targets the latency-bound profile (MfmaUtil 9%, all pipes idle) of the
// per-tile-block version: per-block fixed costs (W loads, launch) now
// amortize over ~3 tiles.
// ===========================================================================
template <int K1, bool FUSE_POOL>
__global__ __launch_bounds__(512, 2) void gin_mlp_persist(
    const ushort* __restrict__ A,
    const ushort* __restrict__ w1t,
    const float* __restrict__ b1,
    const ushort* __restrict__ w2t,
    const float* __restrict__ b2,
    ushort* __restrict__ out,          // planar [8][N][32]
    const int* __restrict__ batch,
    float* __restrict__ sums,
    int M, int nTiles, int nPers)
{
    constexpr int NCH1 = K1 / 8;        // 16 or 32
    constexpr int NSLOT1 = 64 * NCH1;   // 1024 or 2048
    constexpr int NS1 = K1 / 32;        // 4 or 8
    constexpr int PFN = NSLOT1 / 512;   // 2 or 4 short8 per thread per stage

    __shared__ short LsA[NSLOT1 * 8];   // 16 KB (K=128) / 32 KB (K=256)
    __shared__ short LsH[2048 * 8];     // 32 KB

    int t = threadIdx.x;
    int lane = t & 63;
    int wv = t >> 6;                    // 0..7
    int quad = lane >> 4;
    int l15 = lane & 15;
    int swz = l15 & 7;
    int col0 = wv * 32;

    // ---- Preload W1 + W2 slices and biases into registers (once) ----
    short8 w1r[NS1 * 2];
    #pragma unroll
    for (int s = 0; s < NS1; ++s)
        #pragma unroll
        for (int j = 0; j < 2; ++j)
            w1r[s * 2 + j] = *(const short8*)(w1t + (long)(col0 + j * 16 + l15) * K1 + s * 32 + quad * 8);
    short8 w2r[16];
    #pragma unroll
    for (int s = 0; s < 8; ++s)
        #pragma unroll
        for (int j = 0; j < 2; ++j)
            w2r[s * 2 + j] = *(const short8*)(w2t + (long)(col0 + j * 16 + l15) * 256 + s * 32 + quad * 8);
    float bv1[2], bv2[2];
    #pragma unroll
    for (int j = 0; j < 2; ++j) {
        bv1[j] = b1[col0 + j * 16 + l15];
        bv2[j] = b2[col0 + j * 16 + l15];
    }

    // ---- Contiguous tile range for this block ----
    int t0 = (int)(((long)blockIdx.x * nTiles) / nPers);
    int t1 = (int)(((long)(blockIdx.x + 1) * nTiles) / nPers);

    const f32x4 zero = {0.f, 0.f, 0.f, 0.f};

    for (int ti = t0; ti < t1; ++ti) {
        int row0 = ti * 64;

        // ---- Stage A tile (64 x K1, source-side swizzle) into LsA ----
        #pragma unroll
        for (int c = 0; c < PFN; ++c) {
            int s = c * 512 + t;
            int row = s / NCH1;
            int kcs = s & (NCH1 - 1);
            int kc = kcs ^ (row & 7);
            int grow = row0 + row;
            if (grow >= M) grow = M - 1;
            *(short8*)&LsA[s * 8] = *(const short8*)(A + (long)grow * K1 + kc * 8);
        }
        __syncthreads();

        // ---- Layer 1: LDS + registers only ----
        f32x4 acc[4][2];
        #pragma unroll
        for (int i = 0; i < 4; ++i)
            #pragma unroll
            for (int j = 0; j < 2; ++j) acc[i][j] = zero;

        #pragma unroll
        for (int s = 0; s < NS1; ++s) {
            #pragma unroll
            for (int i = 0; i < 4; ++i) {
                int row = i * 16 + l15;
                int slot = row * NCH1 + ((s * 4 + quad) ^ swz);
                short8 a = *(const short8*)&LsA[slot * 8];
                acc[i][0] = __builtin_amdgcn_mfma_f32_16x16x32_bf16(a, w1r[s * 2 + 0], acc[i][0], 0, 0, 0);
                acc[i][1] = __builtin_amdgcn_mfma_f32_16x16x32_bf16(a, w1r[s * 2 + 1], acc[i][1], 0, 0, 0);
            }
        }
        __syncthreads();

        // ---- H = relu(acc + b1) -> LsH (swizzled 64 x 256 bf16) ----
        #pragma unroll
        for (int i = 0; i < 4; ++i)
            #pragma unroll
            for (int j = 0; j < 2; ++j) {
                int col = col0 + j * 16 + l15;
                int kc2 = col >> 3, sub = col & 7;
                #pragma unroll
                for (int r = 0; r < 4; ++r) {
                    int row = i * 16 + quad * 4 + r;
                    int slot = row * 32 + (kc2 ^ (row & 7));
                    float o = fmaxf(acc[i][j][r] + bv1[j], 0.f);
                    LsH[slot * 8 + sub] = (short)f2bf(o);
                }
            }
        __syncthreads();

        // ---- Layer 2: LDS + registers only ----
        #pragma unroll
        for (int i = 0; i < 4; ++i)
            #pragma unroll
            for (int j = 0; j < 2; ++j) acc[i][j] = zero;

        #pragma unroll
        for (int s = 0; s < 8; ++s) {
            #pragma unroll
            for (int i = 0; i < 4; ++i) {
                int row = i * 16 + l15;
                int slot = row * 32 + ((s * 4 + quad) ^ swz);
                short8 a = *(const short8*)&LsH[slot * 8];
                acc[i][0] = __builtin_amdgcn_mfma_f32_16x16x32_bf16(a, w2r[s * 2 + 0], acc[i][0], 0, 0, 0);
                acc[i][1] = __builtin_amdgcn_mfma_f32_16x16x32_bf16(a, w2r[s * 2 + 1], acc[i][1], 0, 0, 0);
            }
        }

        // ---- Epilogue ----
        if constexpr (!FUSE_POOL) {
            #pragma unroll
            for (int i = 0; i < 4; ++i)
                #pragma unroll
                for (int r = 0; r < 4; ++r) {
                    int grow = row0 + i * 16 + quad * 4 + r;
                    if (grow >= M) continue;
                    #pragma unroll
                    for (int j = 0; j < 2; ++j) {
                        int col = col0 + j * 16 + l15;
                        float o = fmaxf(acc[i][j][r] + bv2[j], 0.f);
                        out[(long)(col >> 5) * PLANE_ELEMS + (long)grow * 32 + (col & 31)] = f2bf(o);
                    }
                }
        } else {
            float pacc[2];
            #pragma unroll
            for (int j = 0; j < 2; ++j) pacc[j] = 0.f;
            int cur = -1;
            #pragma unroll
            for (int i = 0; i < 4; ++i) {
                #pragma unroll
                for (int r = 0; r < 4; ++r) {
                    int row = row0 + i * 16 + quad * 4 + r;
                    if (row >= M) continue;
                    int g = batch[row];
                    if (g != cur) {
                        if (cur >= 0) {
                            #pragma unroll
                            for (int j = 0; j < 2; ++j)
                                atomicAdd(&sums[(long)cur * 256 + col0 + j * 16 + l15], pacc[j]);
                        }
                        cur = g;
                        #pragma unroll
                        for (int j = 0; j < 2; ++j) pacc[j] = 0.f;
                    }
                    #pragma unroll
                    for (int j = 0; j < 2; ++j)
                        pacc[j] += fmaxf(acc[i][j][r] + bv2[j], 0.f);
                }
            }
            if (cur >= 0) {
                #pragma unroll
                for (int j = 0; j < 2; ++j)
                    atomicAdd(&sums[(long)cur * 256 + col0 + j * 16 + l15], pacc[j]);
            }
        }
        // no trailing barrier needed: next stage writes LsA; all L1 reads of
        // LsA completed before this tile's post-L1 barrier, and L2 reads only
        // LsH, which the next tile's first two barriers protect.
    }
}

// ===========================================================================
// Head MLP (fp32): one block per graph; count via binary search on batch.
// ===========================================================================
__global__ __launch_bounds__(256) void final_mlp_kernel(
    const float* __restrict__ sums, const int* __restrict__ batch,
    const float* __restrict__ w1, const float* __restrict__ b1,
    const float* __restrict__ w2, const float* __restrict__ b2,
    float* __restrict__ out) {
    __shared__ float row[HID];
    __shared__ float hid[HID];
    __shared__ int cntS;
    int g = blockIdx.x;
    int t = threadIdx.x;
    if (t == 0) {
        int lo = 0, hi = N_NODES;
        while (lo < hi) { int m = (lo + hi) >> 1; if (batch[m] < g) lo = m + 1; else hi = m; }
        int lo2 = lo, hi2 = N_NODES;
        while (lo2 < hi2) { int m = (lo2 + hi2) >> 1; if (batch[m] < g + 1) lo2 = m + 1; else hi2 = m; }
        cntS = lo2 - lo;
    }
    __syncthreads();
    float cnt = fmaxf((float)cntS, 1.0f);
    row[t] = sums[(long)g * HID + t] / cnt;
    __syncthreads();
    float acc = b1[t];
    for (int k = 0; k < HID; ++k) acc += row[k] * w1[k * HID + t];
    hid[t] = fmaxf(acc, 0.f);
    __syncthreads();
    if (t < OUT_C) {
        float o = b2[t];
        for (int k = 0; k < HID; ++k) o += hid[k] * w2[k * OUT_C + t];
        out[(long)g * OUT_C + t] = o;
    }
}

// ---------------------------------------------------------------------------
extern "C" void kernel_launch(void* const* d_in, const int* in_sizes, int n_in,
                              void* d_out, int out_size, void* d_ws, size_t ws_size,
                              hipStream_t stream) {
    const float* x     = (const float*)d_in[0];
    const int*   ei    = (const int*)d_in[1];
    const int*   batch = (const int*)d_in[2];
    const int*   src   = ei;
    const int*   dst   = ei + N_EDGES;

    const float* c_w1[3] = { (const float*)d_in[3],  (const float*)d_in[7],  (const float*)d_in[11] };
    const float* c_b1[3] = { (const float*)d_in[4],  (const float*)d_in[8],  (const float*)d_in[12] };
    const float* c_w2[3] = { (const float*)d_in[5],  (const float*)d_in[9],  (const float*)d_in[13] };
    const float* c_b2[3] = { (const float*)d_in[6],  (const float*)d_in[10], (const float*)d_in[14] };
    const float* out_w1 = (const float*)d_in[15];
    const float* out_b1 = (const float*)d_in[16];
    const float* out_w2 = (const float*)d_in[17];
    const float* out_b2 = (const float*)d_in[18];

    // ---- Workspace layout (16B aligned) ----
    char* p = (char*)d_ws;
    auto alloc = [&](size_t bytes) {
        char* r = p;
        p += (bytes + 15) & ~(size_t)15;
        return r;
    };
    ushort* xbf  = (ushort*)alloc((size_t)N_NODES * IN_C * 2);   // planar [4][N][32]
    ushort* bufA = (ushort*)alloc((size_t)N_NODES * HID * 2);    // planar [8][N][32]
    ushort* bufB = (ushort*)alloc((size_t)N_NODES * HID * 2);    // row-major agg output
    ushort* wt[6];
    wt[0] = (ushort*)alloc((size_t)IN_C * HID * 2);
    for (int i = 1; i < 6; ++i) wt[i] = (ushort*)alloc((size_t)HID * HID * 2);
    float* sums   = (float*)alloc((size_t)N_GRAPHS * HID * 4);
    int* deg       = (int*)alloc((size_t)N_NODES * 4);
    int* rowptr    = (int*)alloc((size_t)(N_NODES + 1) * 4);
    int* blockSums = (int*)alloc(256 * 4);
    int* cursor    = (int*)alloc((size_t)N_NODES * 4);
    int* srcSorted = (int*)alloc((size_t)N_EDGES * 4);

    const int nb = (N_NODES + 255) / 256;

    // ---- Prep: one dispatch for casts + transposes + zeroing ----
    {
        PrepArgs a;
        a.x = x;
        a.w[0] = c_w1[0]; a.w[1] = c_w2[0];
        a.w[2] = c_w1[1]; a.w[3] = c_w2[1];
        a.w[4] = c_w1[2]; a.w[5] = c_w2[2];
        a.xbf = xbf;
        for (int i = 0; i < 6; ++i) a.wt[i] = wt[i];
        a.deg = deg;
        a.sums = sums;
        prep_kernel<<<2048, 256, 0, stream>>>(a);
    }

    // ---- Build CSR by dst ----
    deg_kernel<<<(N_EDGES + 255) / 256, 256, 0, stream>>>(dst, deg);
    scan_block<<<nb, 256, 0, stream>>>(deg, rowptr, blockSums);
    add_offsets_fused<<<nb, 256, 0, stream>>>(rowptr, blockSums, rowptr, cursor, nb);
    bucket_edges<<<(N_EDGES + 255) / 256, 256, 0, stream>>>(src, dst, cursor, srcSorted);

    const int nodeBlks = (N_NODES + 63) / 64;        // 782 (even, needed for PER=2)
    const int aggX128  = nodeBlks * (IN_C / 32);     // 3128
    const int aggX256  = nodeBlks * (HID / 32);      // 6256
    const int NPERS    = 256;                        // persistent MLP grid (1/CU)

    // ---- Layer 0 (C_in = 128) ----
    gin_aggregate_planar<IN_C><<<aggX128, 256, 0, stream>>>(xbf, rowptr, srcSorted, bufB);
    gin_mlp_persist<IN_C, false><<<NPERS, 512, 0, stream>>>(bufB, wt[0], c_b1[0], wt[1], c_b2[0],
                                                            bufA, batch, sums, N_NODES, nodeBlks, NPERS);

    // ---- Layer 1 (C = 256) ----
    gin_aggregate_planar<HID><<<aggX256, 256, 0, stream>>>(bufA, rowptr, srcSorted, bufB);
    gin_mlp_persist<HID, false><<<NPERS, 512, 0, stream>>>(bufB, wt[2], c_b1[1], wt[3], c_b2[1],
                                                           bufA, batch, sums, N_NODES, nodeBlks, NPERS);

    // ---- Layer 2 (C = 256) with fused global mean-pool accumulation ----
    gin_aggregate_planar<HID><<<aggX256, 256, 0, stream>>>(bufA, rowptr, srcSorted, bufB);
    gin_mlp_persist<HID, true><<<NPERS, 512, 0, stream>>>(bufB, wt[4], c_b1[2], wt[5], c_b2[2],
                                                          bufA, batch, sums, N_NODES, nodeBlks, NPERS);

    // ---- Head MLP ----
    final_mlp_kernel<<<N_GRAPHS, 256, 0, stream>>>(sums, batch, out_w1, out_b1,
                                                   out_w2, out_b2, (float*)d_out);
}

// Round 8
// 396.997 us; speedup vs baseline: 1.5357x; 1.0899x over previous
//
#include <hip/hip_runtime.h>

#define N_NODES 50000
#define N_EDGES 800000
#define N_GRAPHS 512
#define IN_C 128
#define HID 256
#define OUT_C 16

typedef __attribute__((ext_vector_type(8))) short short8;
typedef __attribute__((ext_vector_type(4))) float f32x4;

__device__ __forceinline__ float bf2f(unsigned short u) {
    return __uint_as_float(((unsigned int)u) << 16);
}
__device__ __forceinline__ unsigned short f2bf(float f) {
    unsigned int u = __float_as_uint(f);
    u += 0x7fff + ((u >> 16) & 1);   // RNE
    return (unsigned short)(u >> 16);
}

// Planar layout: features stored as [C/32 planes][N_NODES][32 cols] bf16.
// Each plane is 50000*64B = 3.2 MB (contiguous) -> fits one XCD's 4 MB L2.
#define PLANE_ELEMS ((long)N_NODES * 32)

// ===========================================================================
// Prep (single dispatch): x -> bf16 PLANAR, six weight transposes (K x 256
// fp32 -> 256 x K bf16), zero deg, zero sums.
// ===========================================================================
struct PrepArgs {
    const float* x;
    const float* w[6];      // K x 256 row-major; K = 128 for w[0], else 256
    ushort* xbf;            // planar [4][N][32]
    ushort* wt[6];
    int* deg;
    float* sums;
};

__global__ __launch_bounds__(256) void prep_kernel(PrepArgs a) {
    const int X4    = N_NODES * IN_C / 4;
    const int TW    = IN_C * HID;
    const int TH    = HID * HID;
    const int TBASE = X4;
    const int TEND  = TBASE + TW + 5 * TH;
    const int D4    = N_NODES / 4;
    const int DBASE = TEND;
    const int SBASE = DBASE + D4;
    const int S4    = N_GRAPHS * HID / 4;
    const long total = (long)SBASE + S4;

    long stride = (long)gridDim.x * blockDim.x;
    for (long i = (long)blockIdx.x * blockDim.x + threadIdx.x; i < total; i += stride) {
        if (i < X4) {
            float4 v = ((const float4*)a.x)[i];
            ushort4 o;
            o.x = f2bf(v.x); o.y = f2bf(v.y); o.z = f2bf(v.z); o.w = f2bf(v.w);
            long e = i * 4;
            int node = (int)(e >> 7);         // /128
            int col  = (int)(e & 127);
            long off = (long)(col >> 5) * PLANE_ELEMS + (long)node * 32 + (col & 31);
            *(ushort4*)(a.xbf + off) = o;
        } else if (i < TEND) {
            long r = i - TBASE;
            int wi, shift;
            long off;
            if (r < TW) { wi = 0; shift = 7; off = r; }
            else { r -= TW; wi = 1 + (int)(r / TH); shift = 8; off = r % TH; }
            int n = (int)(off >> shift);
            int k = (int)(off - ((long)n << shift));
            a.wt[wi][off] = f2bf(a.w[wi][(long)k * HID + n]);
        } else if (i < SBASE) {
            ((int4*)a.deg)[i - DBASE] = make_int4(0, 0, 0, 0);
        } else {
            ((float4*)a.sums)[i - SBASE] = make_float4(0.f, 0.f, 0.f, 0.f);
        }
    }
}

// ===========================================================================
// CSR build: deg+rank in one atomic pass -> scan -> XCD-sharded atomic-free
// scatter. rank[e] = position of edge e within its dst segment.
// ===========================================================================
__global__ void deg_rank_kernel(const int* __restrict__ dst, int* __restrict__ deg,
                                int* __restrict__ rank) {
    int e = blockIdx.x * blockDim.x + threadIdx.x;
    if (e < N_EDGES) rank[e] = atomicAdd(&deg[dst[e]], 1);
}

__global__ __launch_bounds__(256) void scan_block(const int* __restrict__ deg,
                                                  int* __restrict__ partial,
                                                  int* __restrict__ blockSums) {
    __shared__ int s[256];
    int t = threadIdx.x;
    int i = blockIdx.x * 256 + t;
    int v = (i < N_NODES) ? deg[i] : 0;
    s[t] = v;
    __syncthreads();
    #pragma unroll
    for (int off = 1; off < 256; off <<= 1) {
        int add = (t >= off) ? s[t - off] : 0;
        __syncthreads();
        s[t] += add;
        __syncthreads();
    }
    if (i < N_NODES) partial[i] = s[t] - v;
    if (t == 255) blockSums[blockIdx.x] = s[255];
}

__global__ __launch_bounds__(256) void add_offsets_fused(
    const int* __restrict__ partial, const int* __restrict__ blockSums,
    int* __restrict__ rowptr, int nb) {
    __shared__ int s[256];
    __shared__ int myOff;
    int t = threadIdx.x;
    int v = (t < nb) ? blockSums[t] : 0;
    s[t] = v;
    __syncthreads();
    #pragma unroll
    for (int off = 1; off < 256; off <<= 1) {
        int add = (t >= off) ? s[t - off] : 0;
        __syncthreads();
        s[t] += add;
        __syncthreads();
    }
    if (t == blockIdx.x) myOff = s[t] - v;
    __syncthreads();
    int i = blockIdx.x * 256 + t;
    if (i < N_NODES) rowptr[i] = partial[i] + myOff;
    if (i == 0) rowptr[N_NODES] = N_EDGES;
}

// XCD-sharded scatter: block b -> dst shard (b&7) on XCD (b&7); all writes to
// that shard's ~400KB srcSorted slice stay in one XCD's L2 (no cross-XCD line
// ping-pong). Atomic-free via rank[].
#define NSHARD 8
#define SHARD_SZ ((N_NODES + NSHARD - 1) / NSHARD)   // 6250
#define EDGES_PER_BLK 2048

__global__ __launch_bounds__(256) void scatter_edges_sharded(
    const int* __restrict__ src, const int* __restrict__ dst,
    const int* __restrict__ rank, const int* __restrict__ rowptr,
    int* __restrict__ srcSorted) {
    int b = blockIdx.x;
    int shard = b & 7;
    int chunk = b >> 3;
    int lo = shard * SHARD_SZ;
    int hi = lo + SHARD_SZ;
    int base = chunk * EDGES_PER_BLK + threadIdx.x;
    #pragma unroll
    for (int u = 0; u < EDGES_PER_BLK / 256; ++u) {
        int e = base + u * 256;
        if (e < N_EDGES) {
            int d = dst[e];
            if (d >= lo && d < hi)
                srcSorted[rowptr[d] + rank[e]] = src[e];
        }
    }
}

// ===========================================================================
// Aggregation, planar-in / row-major-out: out[n] = h[n] + sum h[src].
// Cached index loads, nt output stores (round-6: dropped out of top-5).
// ===========================================================================
template <int C>
__global__ __launch_bounds__(256) void gin_aggregate_planar(
    const ushort* __restrict__ hp,     // planar [C/32][N][32]
    const int* __restrict__ rowptr,
    const int* __restrict__ srcIdx,
    ushort* __restrict__ out)          // row-major [N][C]
{
    constexpr int NC  = C / 32;        // 4 (C=128) or 8 (C=256)
    constexpr int PER = 8 / NC;        // XCDs per plane (2 or 1)

    int b  = blockIdx.x;
    int x8 = b & 7;                    // presumed XCD id (round-robin)
    int chunk   = x8 / PER;
    int nodeblk = (b >> 3) * PER + (x8 & (PER - 1));

    int lane = threadIdx.x & 63;
    int wave = threadIdx.x >> 6;
    int grp  = lane >> 2;              // 0..15: node within wave
    int l    = lane & 3;               // 4 lanes x 8 bf16 = 32 cols
    int node = nodeblk * 64 + wave * 16 + grp;
    if (node >= N_NODES) return;

    const ushort* plane = hp + (long)chunk * PLANE_ELEMS + l * 8;

    float acc[8];
    {
        short8 sv = *(const short8*)(plane + (long)node * 32);
        #pragma unroll
        for (int v = 0; v < 8; ++v) acc[v] = bf2f((unsigned short)sv[v]);
    }

    int beg = rowptr[node], end = rowptr[node + 1];
    int k = beg;
    for (; k + 8 <= end; k += 8) {
        int si[8];
        #pragma unroll
        for (int u = 0; u < 8; ++u) si[u] = srcIdx[k + u];
        short8 r[8];
        #pragma unroll
        for (int u = 0; u < 8; ++u) r[u] = *(const short8*)(plane + (long)si[u] * 32);
        #pragma unroll
        for (int u = 0; u < 8; ++u)
            #pragma unroll
            for (int v = 0; v < 8; ++v) acc[v] += bf2f((unsigned short)r[u][v]);
    }
    for (; k + 2 <= end; k += 2) {
        int si0 = srcIdx[k], si1 = srcIdx[k + 1];
        short8 r0 = *(const short8*)(plane + (long)si0 * 32);
        short8 r1 = *(const short8*)(plane + (long)si1 * 32);
        #pragma unroll
        for (int v = 0; v < 8; ++v) acc[v] += bf2f((unsigned short)r0[v]);
        #pragma unroll
        for (int v = 0; v < 8; ++v) acc[v] += bf2f((unsigned short)r1[v]);
    }
    if (k < end) {
        short8 r = *(const short8*)(plane + (long)srcIdx[k] * 32);
        #pragma unroll
        for (int v = 0; v < 8; ++v) acc[v] += bf2f((unsigned short)r[v]);
    }

    short8 o;
    #pragma unroll
    for (int v = 0; v < 8; ++v) o[v] = (short)f2bf(acc[v]);
    __builtin_nontemporal_store(o, (short8*)(out + (long)node * C + chunk * 32 + l * 8));
}

// ===========================================================================
// PERSISTENT fused 2-layer MLP (round-7, kept: removed gin_mlp from top-5).
// Grid = 256 blocks (1/CU); W1+W2 slices live in registers across all tiles.
// ===========================================================================
template <int K1, bool FUSE_POOL>
__global__ __launch_bounds__(512, 2) void gin_mlp_persist(
    const ushort* __restrict__ A,
    const ushort* __restrict__ w1t,
    const float* __restrict__ b1,
    const ushort* __restrict__ w2t,
    const float* __restrict__ b2,
    ushort* __restrict__ out,          // planar [8][N][32]
    const int* __restrict__ batch,
    float* __restrict__ sums,
    int M, int nTiles, int nPers)
{
    constexpr int NCH1 = K1 / 8;        // 16 or 32
    constexpr int NSLOT1 = 64 * NCH1;   // 1024 or 2048
    constexpr int NS1 = K1 / 32;        // 4 or 8
    constexpr int PFN = NSLOT1 / 512;   // 2 or 4 short8 per thread per stage

    __shared__ short LsA[NSLOT1 * 8];   // 16 KB (K=128) / 32 KB (K=256)
    __shared__ short LsH[2048 * 8];     // 32 KB

    int t = threadIdx.x;
    int lane = t & 63;
    int wv = t >> 6;                    // 0..7
    int quad = lane >> 4;
    int l15 = lane & 15;
    int swz = l15 & 7;
    int col0 = wv * 32;

    // ---- Preload W1 + W2 slices and biases into registers (once) ----
    short8 w1r[NS1 * 2];
    #pragma unroll
    for (int s = 0; s < NS1; ++s)
        #pragma unroll
        for (int j = 0; j < 2; ++j)
            w1r[s * 2 + j] = *(const short8*)(w1t + (long)(col0 + j * 16 + l15) * K1 + s * 32 + quad * 8);
    short8 w2r[16];
    #pragma unroll
    for (int s = 0; s < 8; ++s)
        #pragma unroll
        for (int j = 0; j < 2; ++j)
            w2r[s * 2 + j] = *(const short8*)(w2t + (long)(col0 + j * 16 + l15) * 256 + s * 32 + quad * 8);
    float bv1[2], bv2[2];
    #pragma unroll
    for (int j = 0; j < 2; ++j) {
        bv1[j] = b1[col0 + j * 16 + l15];
        bv2[j] = b2[col0 + j * 16 + l15];
    }

    // ---- Contiguous tile range for this block ----
    int t0 = (int)(((long)blockIdx.x * nTiles) / nPers);
    int t1 = (int)(((long)(blockIdx.x + 1) * nTiles) / nPers);

    const f32x4 zero = {0.f, 0.f, 0.f, 0.f};

    for (int ti = t0; ti < t1; ++ti) {
        int row0 = ti * 64;

        // ---- Stage A tile (64 x K1, source-side swizzle) into LsA ----
        #pragma unroll
        for (int c = 0; c < PFN; ++c) {
            int s = c * 512 + t;
            int row = s / NCH1;
            int kcs = s & (NCH1 - 1);
            int kc = kcs ^ (row & 7);
            int grow = row0 + row;
            if (grow >= M) grow = M - 1;
            *(short8*)&LsA[s * 8] = *(const short8*)(A + (long)grow * K1 + kc * 8);
        }
        __syncthreads();

        // ---- Layer 1: LDS + registers only ----
        f32x4 acc[4][2];
        #pragma unroll
        for (int i = 0; i < 4; ++i)
            #pragma unroll
            for (int j = 0; j < 2; ++j) acc[i][j] = zero;

        #pragma unroll
        for (int s = 0; s < NS1; ++s) {
            #pragma unroll
            for (int i = 0; i < 4; ++i) {
                int row = i * 16 + l15;
                int slot = row * NCH1 + ((s * 4 + quad) ^ swz);
                short8 a = *(const short8*)&LsA[slot * 8];
                acc[i][0] = __builtin_amdgcn_mfma_f32_16x16x32_bf16(a, w1r[s * 2 + 0], acc[i][0], 0, 0, 0);
                acc[i][1] = __builtin_amdgcn_mfma_f32_16x16x32_bf16(a, w1r[s * 2 + 1], acc[i][1], 0, 0, 0);
            }
        }
        __syncthreads();

        // ---- H = relu(acc + b1) -> LsH (swizzled 64 x 256 bf16) ----
        #pragma unroll
        for (int i = 0; i < 4; ++i)
            #pragma unroll
            for (int j = 0; j < 2; ++j) {
                int col = col0 + j * 16 + l15;
                int kc2 = col >> 3, sub = col & 7;
                #pragma unroll
                for (int r = 0; r < 4; ++r) {
                    int row = i * 16 + quad * 4 + r;
                    int slot = row * 32 + (kc2 ^ (row & 7));
                    float o = fmaxf(acc[i][j][r] + bv1[j], 0.f);
                    LsH[slot * 8 + sub] = (short)f2bf(o);
                }
            }
        __syncthreads();

        // ---- Layer 2: LDS + registers only ----
        #pragma unroll
        for (int i = 0; i < 4; ++i)
            #pragma unroll
            for (int j = 0; j < 2; ++j) acc[i][j] = zero;

        #pragma unroll
        for (int s = 0; s < 8; ++s) {
            #pragma unroll
            for (int i = 0; i < 4; ++i) {
                int row = i * 16 + l15;
                int slot = row * 32 + ((s * 4 + quad) ^ swz);
                short8 a = *(const short8*)&LsH[slot * 8];
                acc[i][0] = __builtin_amdgcn_mfma_f32_16x16x32_bf16(a, w2r[s * 2 + 0], acc[i][0], 0, 0, 0);
                acc[i][1] = __builtin_amdgcn_mfma_f32_16x16x32_bf16(a, w2r[s * 2 + 1], acc[i][1], 0, 0, 0);
            }
        }

        // ---- Epilogue ----
        if constexpr (!FUSE_POOL) {
            #pragma unroll
            for (int i = 0; i < 4; ++i)
                #pragma unroll
                for (int r = 0; r < 4; ++r) {
                    int grow = row0 + i * 16 + quad * 4 + r;
                    if (grow >= M) continue;
                    #pragma unroll
                    for (int j = 0; j < 2; ++j) {
                        int col = col0 + j * 16 + l15;
                        float o = fmaxf(acc[i][j][r] + bv2[j], 0.f);
                        out[(long)(col >> 5) * PLANE_ELEMS + (long)grow * 32 + (col & 31)] = f2bf(o);
                    }
                }
        } else {
            float pacc[2];
            #pragma unroll
            for (int j = 0; j < 2; ++j) pacc[j] = 0.f;
            int cur = -1;
            #pragma unroll
            for (int i = 0; i < 4; ++i) {
                #pragma unroll
                for (int r = 0; r < 4; ++r) {
                    int row = row0 + i * 16 + quad * 4 + r;
                    if (row >= M) continue;
                    int g = batch[row];
                    if (g != cur) {
                        if (cur >= 0) {
                            #pragma unroll
                            for (int j = 0; j < 2; ++j)
                                atomicAdd(&sums[(long)cur * 256 + col0 + j * 16 + l15], pacc[j]);
                        }
                        cur = g;
                        #pragma unroll
                        for (int j = 0; j < 2; ++j) pacc[j] = 0.f;
                    }
                    #pragma unroll
                    for (int j = 0; j < 2; ++j)
                        pacc[j] += fmaxf(acc[i][j][r] + bv2[j], 0.f);
                }
            }
            if (cur >= 0) {
                #pragma unroll
                for (int j = 0; j < 2; ++j)
                    atomicAdd(&sums[(long)cur * 256 + col0 + j * 16 + l15], pacc[j]);
            }
        }
    }
}

// ===========================================================================
// Head MLP (fp32): one block per graph; count via binary search on batch.
// ===========================================================================
__global__ __launch_bounds__(256) void final_mlp_kernel(
    const float* __restrict__ sums, const int* __restrict__ batch,
    const float* __restrict__ w1, const float* __restrict__ b1,
    const float* __restrict__ w2, const float* __restrict__ b2,
    float* __restrict__ out) {
    __shared__ float row[HID];
    __shared__ float hid[HID];
    __shared__ int cntS;
    int g = blockIdx.x;
    int t = threadIdx.x;
    if (t == 0) {
        int lo = 0, hi = N_NODES;
        while (lo < hi) { int m = (lo + hi) >> 1; if (batch[m] < g) lo = m + 1; else hi = m; }
        int lo2 = lo, hi2 = N_NODES;
        while (lo2 < hi2) { int m = (lo2 + hi2) >> 1; if (batch[m] < g + 1) lo2 = m + 1; else hi2 = m; }
        cntS = lo2 - lo;
    }
    __syncthreads();
    float cnt = fmaxf((float)cntS, 1.0f);
    row[t] = sums[(long)g * HID + t] / cnt;
    __syncthreads();
    float acc = b1[t];
    for (int k = 0; k < HID; ++k) acc += row[k] * w1[k * HID + t];
    hid[t] = fmaxf(acc, 0.f);
    __syncthreads();
    if (t < OUT_C) {
        float o = b2[t];
        for (int k = 0; k < HID; ++k) o += hid[k] * w2[k * OUT_C + t];
        out[(long)g * OUT_C + t] = o;
    }
}

// ---------------------------------------------------------------------------
extern "C" void kernel_launch(void* const* d_in, const int* in_sizes, int n_in,
                              void* d_out, int out_size, void* d_ws, size_t ws_size,
                              hipStream_t stream) {
    const float* x     = (const float*)d_in[0];
    const int*   ei    = (const int*)d_in[1];
    const int*   batch = (const int*)d_in[2];
    const int*   src   = ei;
    const int*   dst   = ei + N_EDGES;

    const float* c_w1[3] = { (const float*)d_in[3],  (const float*)d_in[7],  (const float*)d_in[11] };
    const float* c_b1[3] = { (const float*)d_in[4],  (const float*)d_in[8],  (const float*)d_in[12] };
    const float* c_w2[3] = { (const float*)d_in[5],  (const float*)d_in[9],  (const float*)d_in[13] };
    const float* c_b2[3] = { (const float*)d_in[6],  (const float*)d_in[10], (const float*)d_in[14] };
    const float* out_w1 = (const float*)d_in[15];
    const float* out_b1 = (const float*)d_in[16];
    const float* out_w2 = (const float*)d_in[17];
    const float* out_b2 = (const float*)d_in[18];

    // ---- Workspace layout (16B aligned) ----
    char* p = (char*)d_ws;
    auto alloc = [&](size_t bytes) {
        char* r = p;
        p += (bytes + 15) & ~(size_t)15;
        return r;
    };
    ushort* xbf  = (ushort*)alloc((size_t)N_NODES * IN_C * 2);   // planar [4][N][32]
    ushort* bufA = (ushort*)alloc((size_t)N_NODES * HID * 2);    // planar [8][N][32]
    ushort* bufB = (ushort*)alloc((size_t)N_NODES * HID * 2);    // row-major agg output
    ushort* wt[6];
    wt[0] = (ushort*)alloc((size_t)IN_C * HID * 2);
    for (int i = 1; i < 6; ++i) wt[i] = (ushort*)alloc((size_t)HID * HID * 2);
    float* sums   = (float*)alloc((size_t)N_GRAPHS * HID * 4);
    int* deg       = (int*)alloc((size_t)N_NODES * 4);
    int* rowptr    = (int*)alloc((size_t)(N_NODES + 1) * 4);
    int* blockSums = (int*)alloc(256 * 4);
    int* rank      = (int*)alloc((size_t)N_EDGES * 4);
    int* srcSorted = (int*)alloc((size_t)N_EDGES * 4);

    const int nb = (N_NODES + 255) / 256;

    // ---- Prep: one dispatch for casts + transposes + zeroing ----
    {
        PrepArgs a;
        a.x = x;
        a.w[0] = c_w1[0]; a.w[1] = c_w2[0];
        a.w[2] = c_w1[1]; a.w[3] = c_w2[1];
        a.w[4] = c_w1[2]; a.w[5] = c_w2[2];
        a.xbf = xbf;
        for (int i = 0; i < 6; ++i) a.wt[i] = wt[i];
        a.deg = deg;
        a.sums = sums;
        prep_kernel<<<2048, 256, 0, stream>>>(a);
    }

    // ---- Build CSR by dst: deg+rank -> scan -> sharded atomic-free scatter ----
    deg_rank_kernel<<<(N_EDGES + 255) / 256, 256, 0, stream>>>(dst, deg, rank);
    scan_block<<<nb, 256, 0, stream>>>(deg, rowptr, blockSums);
    add_offsets_fused<<<nb, 256, 0, stream>>>(rowptr, blockSums, rowptr, nb);
    {
        const int chunks = (N_EDGES + EDGES_PER_BLK - 1) / EDGES_PER_BLK;  // 391
        scatter_edges_sharded<<<chunks * NSHARD, 256, 0, stream>>>(src, dst, rank, rowptr, srcSorted);
    }

    const int nodeBlks = (N_NODES + 63) / 64;        // 782 (even, needed for PER=2)
    const int aggX128  = nodeBlks * (IN_C / 32);     // 3128
    const int aggX256  = nodeBlks * (HID / 32);      // 6256
    const int NPERS    = 256;                        // persistent MLP grid (1/CU)

    // ---- Layer 0 (C_in = 128) ----
    gin_aggregate_planar<IN_C><<<aggX128, 256, 0, stream>>>(xbf, rowptr, srcSorted, bufB);
    gin_mlp_persist<IN_C, false><<<NPERS, 512, 0, stream>>>(bufB, wt[0], c_b1[0], wt[1], c_b2[0],
                                                            bufA, batch, sums, N_NODES, nodeBlks, NPERS);

    // ---- Layer 1 (C = 256) ----
    gin_aggregate_planar<HID><<<aggX256, 256, 0, stream>>>(bufA, rowptr, srcSorted, bufB);
    gin_mlp_persist<HID, false><<<NPERS, 512, 0, stream>>>(bufB, wt[2], c_b1[1], wt[3], c_b2[1],
                                                           bufA, batch, sums, N_NODES, nodeBlks, NPERS);

    // ---- Layer 2 (C = 256) with fused global mean-pool accumulation ----
    gin_aggregate_planar<HID><<<aggX256, 256, 0, stream>>>(bufA, rowptr, srcSorted, bufB);
    gin_mlp_persist<HID, true><<<NPERS, 512, 0, stream>>>(bufB, wt[4], c_b1[2], wt[5], c_b2[2],
                                                          bufA, batch, sums, N_NODES, nodeBlks, NPERS);

    // ---- Head MLP ----
    final_mlp_kernel<<<N_GRAPHS, 256, 0, stream>>>(sums, batch, out_w1, out_b1,
                                                   out_w2, out_b2, (float*)d_out);
}